// Round 13
// baseline (1955.067 us; speedup 1.0000x reference)
//
#include <hip/hip_runtime.h>
#include <math.h>

#define FFUNC 1000

typedef __attribute__((ext_vector_type(8))) short s8v;
typedef __attribute__((ext_vector_type(4))) float f4v;

// ---------------- device helpers ----------------
__device__ __forceinline__ float sigf(float x){ return 1.0f/(1.0f+__expf(-x)); }
__device__ __forceinline__ float geluf(float x){
  float u = 1.5957691216057308f * (x + 0.044715f*x*x*x);
  return x / (1.0f + __expf(-u));
}
__device__ __forceinline__ unsigned fkey(float f){
  unsigned u = __float_as_uint(f);
  return (u & 0x80000000u) ? ~u : (u | 0x80000000u);
}
__device__ __forceinline__ float funkey(unsigned k){
  unsigned u = (k & 0x80000000u) ? (k ^ 0x80000000u) : ~k;
  return __uint_as_float(u);
}
__device__ __forceinline__ void atomAddF(float* p, float v){ unsafeAtomicAdd(p, v); }
__device__ __forceinline__ unsigned short bfr(float x){   // f32 -> bf16 RNE
  unsigned u = __float_as_uint(x);
  unsigned r = (u + 0x7FFFu + ((u >> 16) & 1u)) >> 16;
  return (unsigned short)r;
}
__device__ __forceinline__ float b2f(unsigned short v){
  return __uint_as_float((unsigned)v << 16);
}
// f32 -> fp8 e4m3 (OCP), RNE, subnormals->0, clamp 448
__device__ __forceinline__ unsigned char f2fp8(float x){
  unsigned u = __float_as_uint(x);
  unsigned s = (u >> 24) & 0x80u;
  unsigned au = u & 0x7FFFFFFFu;
  if (au > 0x43E00000u) au = 0x43E00000u;           // clamp to 448
  unsigned r = au + 0x7FFFFu + ((au >> 20) & 1u);   // RNE at bit 20
  int e8 = (int)(r >> 23) - 120;
  if (e8 <= 0) return (unsigned char)s;             // flush to zero
  return (unsigned char)(s | (e8 << 3) | ((r >> 20) & 7u));
}
// fp8 e4m3 -> f32, subnormals->0
__device__ __forceinline__ float fp82f(unsigned c){
  unsigned s = (c & 0x80u) << 24;
  unsigned em = c & 0x7Fu;
  unsigned f = s | (((em >> 3) + 120u) << 23) | ((em & 7u) << 20);
  return (em < 8u) ? __uint_as_float(s) : __uint_as_float(f);
}

// ---------------- weight prepack ----------------
__global__ void packw_k(const float* __restrict__ W, unsigned short* __restrict__ out){
  int mat = blockIdx.x;
  const float* w = W + (size_t)mat*16384;
  unsigned short* o = out + (size_t)mat*16384;
  for (int u=0; u<64; u++){
    int oi = u*256 + threadIdx.x;
    int j = oi & 7, l = (oi>>3) & 63, nt = (oi>>9) & 7, kt = oi >> 12;
    float v = w[(size_t)(kt*32 + 8*(l>>4) + j)*128 + nt*16 + (l&15)];
    o[oi] = bfr(v);
  }
}

__global__ void packa_k(const float* __restrict__ A, unsigned short* __restrict__ out){
  int ent = blockIdx.x;
  const float* a = A + (size_t)ent*4096;
  unsigned short* o = out + (size_t)ent*4096;
  for (int u=0; u<16; u++){
    int oi = u*256 + threadIdx.x;
    int j = oi & 7, l = (oi>>3) & 63, nt = (oi>>9) & 1, h = oi >> 10;
    float v = a[(size_t)h*1024 + (size_t)(8*(l>>4)+j)*32 + nt*16 + (l&15)];
    o[oi] = bfr(v);
  }
}

// ---------------- fused K/Q/V projection + per-relation transforms ----------------
// Q -> bf16. K/V transforms staged bf16 in swizzled LDS (0 conflicts),
// fp8-converted in the linear store phase (8B coalesced stores).
struct KX { int styp[4]; int koff[4]; };
__global__ __launch_bounds__(256) void gemm_kqvx_k(
    const void* __restrict__ xdv, const void* __restrict__ xiv, int af32,
    int nd, int ni, int gbd,
    const unsigned short* __restrict__ WK, const unsigned short* __restrict__ WQ,
    const unsigned short* __restrict__ WV,
    const float* __restrict__ bK, const float* __restrict__ bQ, const float* __restrict__ bV,
    const unsigned short* __restrict__ ARpc, const unsigned short* __restrict__ MRpc,
    unsigned short* __restrict__ Qb,
    unsigned char* __restrict__ KRK, unsigned char* __restrict__ KRV, KX kx)
{
  __shared__ __align__(16) unsigned short tile[64*128];
  int blk = blockIdx.x;
  int ty = (blk >= gbd);
  int N = ty ? ni : nd;
  int rbase = (ty ? (blk - gbd) : blk) * 64;
  size_t obase = ty ? (size_t)nd*128 : 0;
  const unsigned short* wk = WK + (ty ? 16384 : 0);
  const unsigned short* wq = WQ + (ty ? 16384 : 0);
  const unsigned short* wv = WV + (ty ? 16384 : 0);
  const float* bk2 = bK + (ty ? 128 : 0);
  const float* bq2 = bQ + (ty ? 128 : 0);
  const float* bv2 = bV + (ty ? 128 : 0);
  const float* Af = (const float*)(ty ? xiv : xdv);
  const unsigned short* Ab = (const unsigned short*)(ty ? xiv : xdv);

  int t = threadIdx.x;
  int l = t & 63, w = t >> 6, b = l >> 4, m = l & 15;
  int arow = rbase + w*16 + m;
  bool rv = arow < N;
  int lrow = w*16 + m;

  s8v axf[4];
  #pragma unroll
  for (int kt=0; kt<4; kt++){
    s8v af = (s8v){0,0,0,0,0,0,0,0};
    if (rv){
      if (af32){
        const float* ap = Af + (size_t)arow*128 + kt*32 + b*8;
        float4 x0 = *(const float4*)ap;
        float4 x1 = *(const float4*)(ap + 4);
        af[0]=(short)bfr(x0.x); af[1]=(short)bfr(x0.y); af[2]=(short)bfr(x0.z); af[3]=(short)bfr(x0.w);
        af[4]=(short)bfr(x1.x); af[5]=(short)bfr(x1.y); af[6]=(short)bfr(x1.z); af[7]=(short)bfr(x1.w);
      } else {
        af = *(const s8v*)(Ab + (size_t)arow*128 + kt*32 + b*8);
      }
    }
    axf[kt] = af;
  }

  f4v acc[8];
  // ================= Q (bf16 out) =================
  #pragma unroll
  for (int nt=0; nt<8; nt++) acc[nt] = (f4v){0,0,0,0};
  #pragma unroll
  for (int kt=0; kt<4; kt++)
    #pragma unroll
    for (int nt=0; nt<8; nt++){
      s8v bf = *(const s8v*)(wq + ((kt*8 + nt)*64 + l)*8);
      acc[nt] = __builtin_amdgcn_mfma_f32_16x16x32_bf16(axf[kt], bf, acc[nt], 0, 0, 0);
    }
  #pragma unroll
  for (int r2=0; r2<4; r2++){
    int trow = w*16 + 4*b + r2;
    #pragma unroll
    for (int nt=0; nt<8; nt++){
      int col = nt*16 + m;
      int ch = (col>>3) ^ (trow&15);
      tile[trow*128 + ch*8 + (col&7)] = bfr(acc[nt][r2] + bq2[col]);
    }
  }
  __syncthreads();
  #pragma unroll
  for (int it=0; it<4; it++){
    int idx = it*256 + t;
    int rr = idx >> 4, cc = idx & 15;
    int orow = rbase + rr;
    if (orow < N)
      *(uint4*)(Qb + obase + (size_t)orow*128 + cc*8) =
          *(const uint4*)(&tile[rr*128 + ((cc ^ (rr&15))*8)]);
  }
  __syncthreads();

  // ================= K -> transform -> KRK (fp8, bf16-staged) =================
  #pragma unroll
  for (int nt=0; nt<8; nt++) acc[nt] = (f4v){0,0,0,0};
  #pragma unroll
  for (int kt=0; kt<4; kt++)
    #pragma unroll
    for (int nt=0; nt<8; nt++){
      s8v bf = *(const s8v*)(wk + ((kt*8 + nt)*64 + l)*8);
      acc[nt] = __builtin_amdgcn_mfma_f32_16x16x32_bf16(axf[kt], bf, acc[nt], 0, 0, 0);
    }
  #pragma unroll
  for (int r2=0; r2<4; r2++){
    int trow = w*16 + 4*b + r2;
    #pragma unroll
    for (int nt=0; nt<8; nt++){
      int col = nt*16 + m;
      int ch = (col>>3) ^ (trow&15);
      tile[trow*128 + ch*8 + (col&7)] = bfr(acc[nt][r2] + bk2[col]);
    }
  }
  __syncthreads();
  {
    s8v kf[4];
    #pragma unroll
    for (int h=0; h<4; h++){
      int ch = (h*4 + b) ^ (lrow&15);
      kf[h] = *(const s8v*)(&tile[lrow*128 + ch*8]);
    }
    __syncthreads();
    #pragma unroll
    for (int r=0; r<4; r++){
      if (kx.styp[r] != ty) continue;
      const unsigned short* Ap = ARpc + r*4096;
      f4v xa[8];
      #pragma unroll
      for (int i=0;i<8;i++) xa[i] = (f4v){0,0,0,0};
      #pragma unroll
      for (int h=0; h<4; h++)
        #pragma unroll
        for (int n2=0; n2<2; n2++){
          s8v bf = *(const s8v*)(Ap + ((h*2 + n2)*64 + l)*8);
          xa[h*2+n2] = __builtin_amdgcn_mfma_f32_16x16x32_bf16(kf[h], bf, xa[h*2+n2], 0, 0, 0);
        }
      // bf16 staged, swizzled (conflict-free)
      #pragma unroll
      for (int r2=0; r2<4; r2++){
        int trow = w*16 + 4*b + r2;
        #pragma unroll
        for (int h=0; h<4; h++)
          #pragma unroll
          for (int n2=0; n2<2; n2++){
            int col = h*32 + n2*16 + m;
            int ch = (col>>3) ^ (trow&15);
            tile[trow*128 + ch*8 + (col&7)] = bfr(xa[h*2+n2][r2]);
          }
      }
      __syncthreads();
      int ko = kx.koff[r];
      #pragma unroll
      for (int it=0; it<4; it++){
        int idx = it*256 + t;
        int rr = idx >> 4, cc = idx & 15;
        int orow = rbase + rr;
        if (orow < N){
          const unsigned short* sp = &tile[rr*128 + ((cc ^ (rr&15))*8)];
          ushort4 p0 = *(const ushort4*)sp;
          ushort4 p1 = *(const ushort4*)(sp + 4);
          unsigned char ob[8];
          ob[0]=f2fp8(b2f(p0.x)); ob[1]=f2fp8(b2f(p0.y));
          ob[2]=f2fp8(b2f(p0.z)); ob[3]=f2fp8(b2f(p0.w));
          ob[4]=f2fp8(b2f(p1.x)); ob[5]=f2fp8(b2f(p1.y));
          ob[6]=f2fp8(b2f(p1.z)); ob[7]=f2fp8(b2f(p1.w));
          *(uint2*)(KRK + (size_t)(ko + orow)*128 + cc*8) = *(const uint2*)ob;
        }
      }
      __syncthreads();
    }
  }

  // ================= V -> transform -> KRV (fp8, bf16-staged) =================
  #pragma unroll
  for (int nt=0; nt<8; nt++) acc[nt] = (f4v){0,0,0,0};
  #pragma unroll
  for (int kt=0; kt<4; kt++)
    #pragma unroll
    for (int nt=0; nt<8; nt++){
      s8v bf = *(const s8v*)(wv + ((kt*8 + nt)*64 + l)*8);
      acc[nt] = __builtin_amdgcn_mfma_f32_16x16x32_bf16(axf[kt], bf, acc[nt], 0, 0, 0);
    }
  #pragma unroll
  for (int r2=0; r2<4; r2++){
    int trow = w*16 + 4*b + r2;
    #pragma unroll
    for (int nt=0; nt<8; nt++){
      int col = nt*16 + m;
      int ch = (col>>3) ^ (trow&15);
      tile[trow*128 + ch*8 + (col&7)] = bfr(acc[nt][r2] + bv2[col]);
    }
  }
  __syncthreads();
  {
    s8v vf[4];
    #pragma unroll
    for (int h=0; h<4; h++){
      int ch = (h*4 + b) ^ (lrow&15);
      vf[h] = *(const s8v*)(&tile[lrow*128 + ch*8]);
    }
    __syncthreads();
    #pragma unroll
    for (int r=0; r<4; r++){
      if (kx.styp[r] != ty) continue;
      const unsigned short* Ap = MRpc + r*4096;
      f4v xa[8];
      #pragma unroll
      for (int i=0;i<8;i++) xa[i] = (f4v){0,0,0,0};
      #pragma unroll
      for (int h=0; h<4; h++)
        #pragma unroll
        for (int n2=0; n2<2; n2++){
          s8v bf = *(const s8v*)(Ap + ((h*2 + n2)*64 + l)*8);
          xa[h*2+n2] = __builtin_amdgcn_mfma_f32_16x16x32_bf16(vf[h], bf, xa[h*2+n2], 0, 0, 0);
        }
      #pragma unroll
      for (int r2=0; r2<4; r2++){
        int trow = w*16 + 4*b + r2;
        #pragma unroll
        for (int h=0; h<4; h++)
          #pragma unroll
          for (int n2=0; n2<2; n2++){
            int col = h*32 + n2*16 + m;
            int ch = (col>>3) ^ (trow&15);
            tile[trow*128 + ch*8 + (col&7)] = bfr(xa[h*2+n2][r2]);
          }
      }
      __syncthreads();
      int ko = kx.koff[r];
      #pragma unroll
      for (int it=0; it<4; it++){
        int idx = it*256 + t;
        int rr = idx >> 4, cc = idx & 15;
        int orow = rbase + rr;
        if (orow < N){
          const unsigned short* sp = &tile[rr*128 + ((cc ^ (rr&15))*8)];
          ushort4 p0 = *(const ushort4*)sp;
          ushort4 p1 = *(const ushort4*)(sp + 4);
          unsigned char ob[8];
          ob[0]=f2fp8(b2f(p0.x)); ob[1]=f2fp8(b2f(p0.y));
          ob[2]=f2fp8(b2f(p0.z)); ob[3]=f2fp8(b2f(p0.w));
          ob[4]=f2fp8(b2f(p1.x)); ob[5]=f2fp8(b2f(p1.y));
          ob[6]=f2fp8(b2f(p1.z)); ob[7]=f2fp8(b2f(p1.w));
          *(uint2*)(KRV + (size_t)(ko + orow)*128 + cc*8) = *(const uint2*)ob;
        }
      }
      __syncthreads();
    }
  }
}

// ---------------- fused both-direction epilogue (kills O1b) ----------------
__global__ __launch_bounds__(256) void gemm_epi2_k(
    const unsigned short* __restrict__ AGG0, const float* __restrict__ DEN0,
    const unsigned short* __restrict__ AGG1, const float* __restrict__ DEN1,
    int nd, int ni, int gbd,
    const unsigned short* __restrict__ WAb, const float* __restrict__ bAb,
    const void* __restrict__ xin_dv, const void* __restrict__ xin_iv, int xf32,
    unsigned short* __restrict__ out, const float* __restrict__ skp)
{
  __shared__ __align__(16) unsigned short tA[64*128];
  __shared__ __align__(16) unsigned short tB[64*128];
  int blk = blockIdx.x;
  int ty = (blk >= gbd);
  int N = ty ? ni : nd;
  int rbase = (ty ? (blk - gbd) : blk) * 64;
  int goff = ty ? nd : 0;
  const unsigned short* wa0 = WAb + (size_t)ty*16384;
  const unsigned short* wa1 = WAb + (size_t)(2+ty)*16384;
  const float* ba0 = bAb + ty*128;
  const float* ba1 = bAb + (2+ty)*128;
  const float* xinF = (const float*)(ty ? xin_iv : xin_dv);
  const unsigned short* xinB = (const unsigned short*)(ty ? xin_iv : xin_dv);
  float s0 = sigf(skp[ty]),     s0c = 1.0f - s0;
  float s1 = sigf(skp[2 + ty]), s1c = 1.0f - s1;

  int t = threadIdx.x;
  int l = t & 63, w = t >> 6, b = l >> 4, m = l & 15;
  int arow = rbase + w*16 + m;
  bool rv = arow < N;
  size_t grow = (size_t)(goff + (rv ? arow : 0));

  #pragma unroll
  for (int dir=0; dir<2; dir++){
    const unsigned short* AG = dir ? AGG1 : AGG0;
    const float* DN = dir ? DEN1 : DEN0;
    const unsigned short* wa = dir ? wa1 : wa0;
    unsigned short* tl = dir ? tB : tA;
    f4v acc[8];
    #pragma unroll
    for (int nt=0; nt<8; nt++) acc[nt] = (f4v){0,0,0,0};
    float4 dv4 = make_float4(1.f,1.f,1.f,1.f);
    if (rv){
      float4 dr = *(const float4*)(DN + grow*4);
      dv4.x = 1.0f / fmaxf(dr.x, 1e-16f);
      dv4.y = 1.0f / fmaxf(dr.y, 1e-16f);
      dv4.z = 1.0f / fmaxf(dr.z, 1e-16f);
      dv4.w = 1.0f / fmaxf(dr.w, 1e-16f);
    }
    #pragma unroll
    for (int kt=0; kt<4; kt++){
      s8v af = (s8v){0,0,0,0,0,0,0,0};
      if (rv){
        float dv = (kt==0)?dv4.x:(kt==1)?dv4.y:(kt==2)?dv4.z:dv4.w;
        s8v ag = *(const s8v*)(AG + grow*128 + kt*32 + b*8);
        #pragma unroll
        for (int jj=0; jj<8; jj++)
          af[jj] = (short)bfr(geluf(b2f((unsigned short)ag[jj]) * dv));
      }
      #pragma unroll
      for (int nt=0; nt<8; nt++){
        s8v bf = *(const s8v*)(wa + ((kt*8 + nt)*64 + l)*8);
        acc[nt] = __builtin_amdgcn_mfma_f32_16x16x32_bf16(af, bf, acc[nt], 0, 0, 0);
      }
    }
    #pragma unroll
    for (int r2=0; r2<4; r2++){
      int trow = w*16 + 4*b + r2;
      #pragma unroll
      for (int nt=0; nt<8; nt++){
        int col = nt*16 + m;
        int ch = (col>>3) ^ (trow&15);
        tl[trow*128 + ch*8 + (col&7)] = bfr(acc[nt][r2]);
      }
    }
  }
  __syncthreads();
  #pragma unroll
  for (int it=0; it<4; it++){
    int idx = it*256 + t;
    int rr = idx >> 4, cc = idx & 15;
    int orow = rbase + rr;
    if (orow >= N) continue;
    size_t gr = (size_t)(goff + orow);
    int so = rr*128 + ((cc ^ (rr&15))*8);
    float a0[8], a1[8];
    {
      ushort4 p0 = *(const ushort4*)(&tA[so]);
      ushort4 p1 = *(const ushort4*)(&tA[so+4]);
      a0[0]=b2f(p0.x); a0[1]=b2f(p0.y); a0[2]=b2f(p0.z); a0[3]=b2f(p0.w);
      a0[4]=b2f(p1.x); a0[5]=b2f(p1.y); a0[6]=b2f(p1.z); a0[7]=b2f(p1.w);
      ushort4 q0 = *(const ushort4*)(&tB[so]);
      ushort4 q1 = *(const ushort4*)(&tB[so+4]);
      a1[0]=b2f(q0.x); a1[1]=b2f(q0.y); a1[2]=b2f(q0.z); a1[3]=b2f(q0.w);
      a1[4]=b2f(q1.x); a1[5]=b2f(q1.y); a1[6]=b2f(q1.z); a1[7]=b2f(q1.w);
    }
    int c0 = cc*8;
    float4 b00 = *(const float4*)(ba0 + c0);
    float4 b01 = *(const float4*)(ba0 + c0 + 4);
    float4 b10 = *(const float4*)(ba1 + c0);
    float4 b11 = *(const float4*)(ba1 + c0 + 4);
    float bb0[8] = {b00.x,b00.y,b00.z,b00.w,b01.x,b01.y,b01.z,b01.w};
    float bb1[8] = {b10.x,b10.y,b10.z,b10.w,b11.x,b11.y,b11.z,b11.w};
    float xv[8];
    if (xf32){
      float4 x0 = *(const float4*)(xinF + (size_t)orow*128 + c0);
      float4 x1 = *(const float4*)(xinF + (size_t)orow*128 + c0 + 4);
      xv[0]=x0.x; xv[1]=x0.y; xv[2]=x0.z; xv[3]=x0.w;
      xv[4]=x1.x; xv[5]=x1.y; xv[6]=x1.z; xv[7]=x1.w;
    } else {
      ushort4 x0 = *(const ushort4*)(xinB + (size_t)orow*128 + c0);
      ushort4 x1 = *(const ushort4*)(xinB + (size_t)orow*128 + c0 + 4);
      xv[0]=b2f(x0.x); xv[1]=b2f(x0.y); xv[2]=b2f(x0.z); xv[3]=b2f(x0.w);
      xv[4]=b2f(x1.x); xv[5]=b2f(x1.y); xv[6]=b2f(x1.z); xv[7]=b2f(x1.w);
    }
    unsigned short ov[8];
    #pragma unroll
    for (int q=0; q<8; q++){
      float o1 = s0*(a0[q] + bb0[q]) + s0c*xv[q];
      float o2 = s1*(a1[q] + bb1[q]) + s1c*xv[q];
      ov[q] = bfr(fmaxf(0.5f*o1 + 0.5f*o2, 0.f));
    }
    *(uint4*)(out + gr*128 + c0) = *(const uint4*)ov;
  }
}

// ---------------- merged CSR build ----------------
struct ScanDesc { int n[8]; };

struct HD {
  int blk0[9];
  const int* dst[8];
  const int* src[8];
  int E[8];
  int cnto[8];
  int permo[8];
};
__global__ void csr_hist_all_k(HD d, int* __restrict__ cnt){
  int b = blockIdx.x;
  int r = 0;
  while (r < 7 && b >= d.blk0[r+1]) r++;
  int e = (b - d.blk0[r])*256 + threadIdx.x;
  if (e < d.E[r]) atomicAdd(&cnt[d.cnto[r] + d.dst[r][e]], 1);
}
__global__ void csr_fill_all_k(HD d, int* __restrict__ curs, int* __restrict__ perm){
  int b = blockIdx.x;
  int r = 0;
  while (r < 7 && b >= d.blk0[r+1]) r++;
  int e = (b - d.blk0[r])*256 + threadIdx.x;
  if (e < d.E[r]){
    int pos = atomicAdd(&curs[d.cnto[r] + d.dst[r][e]], 1);
    perm[d.permo[r] + pos] = d.src[r][e] | ((r & 3) << 24);
  }
}

// ---------------- parallel 3-phase scan ----------------
__global__ __launch_bounds__(1024) void scan_p1(ScanDesc sd, const int* __restrict__ offs,
                                                int* __restrict__ part, int NO, int MAXT){
  int ent = blockIdx.y, tile = blockIdx.x;
  int n = sd.n[ent];
  int i = tile*1024 + threadIdx.x;
  int v = (i < n) ? offs[(size_t)ent*NO + i] : 0;
  #pragma unroll
  for (int d2=1; d2<64; d2<<=1) v += __shfl_xor(v, d2, 64);
  __shared__ int ws_[16];
  int lane = threadIdx.x & 63, wv = threadIdx.x >> 6;
  if (lane == 0) ws_[wv] = v;
  __syncthreads();
  if (threadIdx.x == 0){
    int s = 0;
    #pragma unroll
    for (int k=0;k<16;k++) s += ws_[k];
    part[ent*MAXT + tile] = s;
  }
}

__global__ __launch_bounds__(1024) void scan_p2(int* __restrict__ part, int MAXT, int nent){
  int tid = threadIdx.x, lane = tid & 63, wv = tid >> 6;
  __shared__ int wsum[16];
  __shared__ int woff[17];
  for (int ent=0; ent<nent; ent++){
    int v = (tid < MAXT) ? part[ent*MAXT + tid] : 0;
    int s = v;
    #pragma unroll
    for (int d2=1; d2<64; d2<<=1){
      int t2 = __shfl_up(s, d2, 64);
      if (lane >= d2) s += t2;
    }
    if (lane == 63) wsum[wv] = s;
    __syncthreads();
    if (wv == 0 && lane < 16){
      int x = wsum[lane];
      #pragma unroll
      for (int d2=1; d2<16; d2<<=1){
        int t2 = __shfl_up(x, d2, 64);
        if (lane >= d2) x += t2;
      }
      woff[lane+1] = x;
      if (lane == 0) woff[0] = 0;
    }
    __syncthreads();
    if (tid < MAXT) part[ent*MAXT + tid] = woff[wv] + s - v;
    __syncthreads();
  }
}

__global__ __launch_bounds__(1024) void scan_p3(ScanDesc sd, int* __restrict__ offs,
                                                int* __restrict__ curs,
                                                const int* __restrict__ part, int NO, int MAXT){
  int ent = blockIdx.y, tile = blockIdx.x;
  int n = sd.n[ent];
  int i = tile*1024 + threadIdx.x;
  int v = (i < n) ? offs[(size_t)ent*NO + i] : 0;
  int lane = threadIdx.x & 63, wv = threadIdx.x >> 6;
  int s = v;
  #pragma unroll
  for (int d2=1; d2<64; d2<<=1){
    int t2 = __shfl_up(s, d2, 64);
    if (lane >= d2) s += t2;
  }
  __shared__ int wsum[16];
  __shared__ int woff[17];
  if (lane == 63) wsum[wv] = s;
  __syncthreads();
  if (wv == 0 && lane < 16){
    int x = wsum[lane];
    #pragma unroll
    for (int d2=1; d2<16; d2<<=1){
      int t2 = __shfl_up(x, d2, 64);
      if (lane >= d2) x += t2;
    }
    woff[lane+1] = x;
    if (lane == 0) woff[0] = 0;
  }
  __syncthreads();
  int excl = part[ent*MAXT + tile] + woff[wv] + s - v;
  if (i < n){
    offs[(size_t)ent*NO + i] = excl;
    curs[(size_t)ent*NO + i] = excl;
  }
  if (i == n-1) offs[(size_t)ent*NO + n] = excl + v;
}

// ---------------- function-CSR build ----------------
__global__ void fhist_k(const int* __restrict__ fd, const int* __restrict__ fi,
                        int Nd, int Ni, int* __restrict__ cnt){
  int nt = Nd + Ni;
  for (int n = blockIdx.x*256 + threadIdx.x; n < nt; n += gridDim.x*256){
    int f = (n < Nd) ? fd[n] : fi[n-Nd];
    atomicAdd(&cnt[f], 1);
  }
}
__global__ void ffill_k(const int* __restrict__ fd, const int* __restrict__ fi,
                        int Nd, int Ni, int* __restrict__ curs, int* __restrict__ perm){
  int nt = Nd + Ni;
  for (int n = blockIdx.x*256 + threadIdx.x; n < nt; n += gridDim.x*256){
    int f = (n < Nd) ? fd[n] : fi[n-Nd];
    int pos = atomicAdd(&curs[f], 1);
    perm[pos] = n;
  }
}

// ---------------- E12 merged: online-softmax edge aggregation (fp8 K/V) ----------------
struct MD { int koff[4]; };
__global__ __launch_bounds__(256) void e12m_k(
    const unsigned char* __restrict__ KRK, const unsigned char* __restrict__ KRV,
    const unsigned short* __restrict__ Qb,
    const int* __restrict__ offs, const int* __restrict__ perm, int nrows,
    const float* __restrict__ pr,
    unsigned short* __restrict__ aggb, float* __restrict__ den, MD md)
{
  int gidx = blockIdx.x*256 + threadIdx.x;
  int node = gidx >> 5; if (node >= nrows) return;
  int sub = gidx & 31, h = sub >> 3, j = sub & 7;
  int o0 = offs[node], o1 = offs[node+1];
  unsigned short* ap = aggb + (size_t)node*128 + h*32 + j*4;
  if (o0 == o1){
    *(ushort4*)ap = make_ushort4(0,0,0,0);
    if (j == 0) den[(size_t)node*4 + h] = 0.f;
    return;
  }
  ushort4 qa = *(const ushort4*)(Qb + (size_t)node*128 + h*32 + j*4);
  float q0=b2f(qa.x), q1=b2f(qa.y), q2=b2f(qa.z), q3=b2f(qa.w);
  float scl[4];
  #pragma unroll
  for (int r=0;r<4;r++) scl[r] = pr[r*4 + h] * 0.17677669529663687f;  // 1/sqrt(32)
  float mx = -INFINITY, ds = 0.f;
  float4 acc = make_float4(0.f,0.f,0.f,0.f);
  for (int i=o0; i<o1; ++i){
    int pk = perm[i];
    int src = pk & 0xFFFFFF, rel = pk >> 24;
    size_t rowo = (size_t)(md.koff[rel] + src)*128 + h*32 + j*4;
    unsigned ku = *(const unsigned*)(KRK + rowo);
    unsigned vu = *(const unsigned*)(KRV + rowo);
    float p = fp82f(ku & 255u)*q0 + fp82f((ku>>8)&255u)*q1
            + fp82f((ku>>16)&255u)*q2 + fp82f(ku>>24)*q3;
    p += __shfl_xor(p, 1, 8);
    p += __shfl_xor(p, 2, 8);
    p += __shfl_xor(p, 4, 8);
    float lg = p * scl[rel];
    float nm = fmaxf(mx, lg);
    float corr = __expf(mx - nm);
    float ev = __expf(lg - nm);
    acc.x = acc.x*corr + ev*fp82f(vu & 255u);
    acc.y = acc.y*corr + ev*fp82f((vu>>8)&255u);
    acc.z = acc.z*corr + ev*fp82f((vu>>16)&255u);
    acc.w = acc.w*corr + ev*fp82f(vu>>24);
    ds = ds*corr + ev;
    mx = nm;
  }
  *(ushort4*)ap = make_ushort4(bfr(acc.x), bfr(acc.y), bfr(acc.z), bfr(acc.w));
  if (j == 0) den[(size_t)node*4 + h] = ds;
}

// ---------------- plain MFMA GEMM (cf only; optional per-row divide) ----------------
__global__ __launch_bounds__(256) void gemmb_k(
    const float* __restrict__ A, int N,
    const unsigned short* __restrict__ Wp, const float* __restrict__ bias,
    float* __restrict__ outf, int mode, const float* __restrict__ rdiv)
{
  int t = threadIdx.x;
  int l = t & 63, w = t >> 6, b = l >> 4, m = l & 15;
  int arow = blockIdx.x*64 + w*16 + m;
  bool rv = arow < N;
  float dv = 1.0f;
  if (rv && rdiv) dv = 1.0f / fmaxf(rdiv[arow], 1.0f);
  f4v acc[8];
  #pragma unroll
  for (int nt=0; nt<8; nt++) acc[nt] = (f4v){0,0,0,0};
  #pragma unroll
  for (int kt=0; kt<4; kt++){
    s8v af = (s8v){0,0,0,0,0,0,0,0};
    if (rv){
      const float* ap = A + (size_t)arow*128 + kt*32 + b*8;
      float4 x0 = *(const float4*)ap;
      float4 x1 = *(const float4*)(ap + 4);
      af[0]=(short)bfr(x0.x*dv); af[1]=(short)bfr(x0.y*dv); af[2]=(short)bfr(x0.z*dv); af[3]=(short)bfr(x0.w*dv);
      af[4]=(short)bfr(x1.x*dv); af[5]=(short)bfr(x1.y*dv); af[6]=(short)bfr(x1.z*dv); af[7]=(short)bfr(x1.w*dv);
    }
    #pragma unroll
    for (int nt=0; nt<8; nt++){
      s8v bf = *(const s8v*)(Wp + ((kt*8 + nt)*64 + l)*8);
      acc[nt] = __builtin_amdgcn_mfma_f32_16x16x32_bf16(af, bf, acc[nt], 0, 0, 0);
    }
  }
  #pragma unroll
  for (int r2=0; r2<4; r2++){
    int orow = blockIdx.x*64 + w*16 + 4*b + r2;
    if (orow >= N) continue;
    #pragma unroll
    for (int nt=0; nt<8; nt++){
      int col = nt*16 + m;
      float v = acc[nt][r2];
      if (bias) v += bias[col];
      if (mode == 1) v = tanhf(v);
      outf[(size_t)orow*128 + col] = v;
    }
  }
}

// ---------------- func pool (CSR, bf16 X): sums + counts ----------------
__global__ __launch_bounds__(256) void f1c_k(const unsigned short* __restrict__ X,
    const int* __restrict__ foffs, const int* __restrict__ fperm,
    float* __restrict__ fsum, float* __restrict__ fcnt)
{
  __shared__ __align__(16) float red[4][128];
  int t = threadIdx.x, wv = t >> 6, lane = t & 63;
  int f = blockIdx.x;
  int o0 = foffs[f], o1 = foffs[f+1];
  float a0 = 0, a1 = 0;
  for (int i = o0 + wv; i < o1; i += 4){
    ushort2 x = *(const ushort2*)(X + (size_t)fperm[i]*128 + lane*2);
    a0 += b2f(x.x); a1 += b2f(x.y);
  }
  red[wv][lane*2] = a0; red[wv][lane*2+1] = a1;
  __syncthreads();
  if (t < 128)
    fsum[(size_t)f*128 + t] = red[0][t] + red[1][t] + red[2][t] + red[3][t];
  if (t == 0) fcnt[f] = (float)(o1 - o0);
}

// ---------------- func pool (CSR, bf16 X): femb(bf16) + global attention pool ----------------
__global__ __launch_bounds__(256) void f23c_k(const unsigned short* __restrict__ X,
    const int* __restrict__ foffs, const int* __restrict__ fperm,
    const float* __restrict__ cf, const float* __restrict__ attc,
    unsigned short* __restrict__ fembb, float* __restrict__ pooled)
{
  __shared__ __align__(16) float rede[4][128];
  __shared__ __align__(16) float redp[4][128];
  int t = threadIdx.x, wv = t >> 6, lane = t & 63;
  int f = blockIdx.x;
  int o0 = foffs[f], o1 = foffs[f+1];
  float c0 = cf[(size_t)f*128 + lane*2], c1 = cf[(size_t)f*128 + lane*2 + 1];
  float t0 = attc[lane*2], t1 = attc[lane*2 + 1];
  float e0=0, e1=0, p0=0, p1=0;
  for (int i = o0 + wv; i < o1; i += 4){
    ushort2 xr = *(const ushort2*)(X + (size_t)fperm[i]*128 + lane*2);
    float vx = b2f(xr.x), vy = b2f(xr.y);
    union { double d; float2 f2; } u;
    u.f2.x = vx*c0 + vy*c1;
    u.f2.y = vx*t0 + vy*t1;
    #pragma unroll
    for (int m2=1; m2<64; m2<<=1){
      union { double d; float2 f2; } v;
      v.d = __shfl_xor(u.d, m2, 64);
      u.f2.x += v.f2.x; u.f2.y += v.f2.y;
    }
    float s1 = sigf(u.f2.x), s2 = sigf(u.f2.y);
    e0 += vx*s1; e1 += vy*s1;
    p0 += vx*s2; p1 += vy*s2;
  }
  rede[wv][lane*2] = e0; rede[wv][lane*2+1] = e1;
  redp[wv][lane*2] = p0; redp[wv][lane*2+1] = p1;
  __syncthreads();
  if (t < 128){
    fembb[(size_t)f*128 + t] = bfr(rede[0][t] + rede[1][t] + rede[2][t] + rede[3][t]);
    float pp = redp[0][t] + redp[1][t] + redp[2][t] + redp[3][t];
    atomAddF(&pooled[t], pp);
  }
}

// ---------------- attention-pool context (parallel colsum) ----------------
__global__ __launch_bounds__(1024) void attc2_k(const float* __restrict__ fsum, float Ninv,
                                                const float* __restrict__ Watt,
                                                float* __restrict__ attc)
{
  __shared__ float part[8][128];
  __shared__ float mean[128];
  int t = threadIdx.x;
  int j = t & 127, ch = t >> 7;
  float a = 0;
  for (int f = ch; f < FFUNC; f += 8) a += fsum[(size_t)f*128 + j];
  part[ch][j] = a;
  __syncthreads();
  if (t < 128){
    float m = 0;
    #pragma unroll
    for (int c=0;c<8;c++) m += part[c][t];
    mean[t] = m * Ninv;
  }
  __syncthreads();
  if (t < 128){
    float c = 0;
    for (int k=0;k<128;k++) c += mean[k]*Watt[(size_t)k*128 + t];
    attc[t] = tanhf(c);
  }
}

// ---------------- MFMA similarity GEMM (NT, bf16) + min/max ----------------
__global__ __launch_bounds__(256) void gemmnt_b(const unsigned short* __restrict__ fa,
                                                const unsigned short* __restrict__ fb,
                                                float* __restrict__ sc,
                                                unsigned* __restrict__ mmk)
{
  int t = threadIdx.x;
  int l = t & 63, w = t >> 6, b = l >> 4, m = l & 15;
  int rowbase = blockIdx.y*64 + w*16;
  int colbase = blockIdx.x*64;
  f4v acc[4];
  #pragma unroll
  for (int nt=0; nt<4; nt++) acc[nt] = (f4v){0,0,0,0};
  #pragma unroll
  for (int kt=0; kt<4; kt++){
    int arow = rowbase + m;
    s8v af = (s8v){0,0,0,0,0,0,0,0};
    if (arow < FFUNC) af = *(const s8v*)(fa + (size_t)arow*128 + kt*32 + b*8);
    #pragma unroll
    for (int nt=0; nt<4; nt++){
      int brow = colbase + nt*16 + m;
      s8v bf = (s8v){0,0,0,0,0,0,0,0};
      if (brow < FFUNC) bf = *(const s8v*)(fb + (size_t)brow*128 + kt*32 + b*8);
      acc[nt] = __builtin_amdgcn_mfma_f32_16x16x32_bf16(af, bf, acc[nt], 0, 0, 0);
    }
  }
  float mn = INFINITY, mx = -INFINITY;
  #pragma unroll
  for (int nt=0; nt<4; nt++){
    #pragma unroll
    for (int r2=0; r2<4; r2++){
      int row = rowbase + 4*b + r2;
      int col = colbase + nt*16 + m;
      if (row < FFUNC && col < FFUNC){
        float v = acc[nt][r2];
        sc[(size_t)row*FFUNC + col] = v;
        mn = fminf(mn, v); mx = fmaxf(mx, v);
      }
    }
  }
  __shared__ float smn[256], smx[256];
  smn[t]=mn; smx[t]=mx; __syncthreads();
  for (int o=128;o>0;o>>=1){
    if (t<o){ smn[t]=fminf(smn[t],smn[t+o]); smx[t]=fmaxf(smx[t],smx[t+o]); }
    __syncthreads();
  }
  if (t==0){ atomicMin(&mmk[0], fkey(smn[0])); atomicMax(&mmk[1], fkey(smx[0])); }
}

__global__ void hist_init_k(unsigned* mmk, unsigned* hist){
  int t = threadIdx.x;
  if (t==0){ mmk[0]=0xFFFFFFFFu; mmk[1]=0u; }
  if (t<16) hist[t]=0u;
}

__global__ void hist_k(const float* __restrict__ sc, const unsigned* __restrict__ mmk,
                       unsigned* __restrict__ hist)
{
  __shared__ unsigned hl[16];
  int t = threadIdx.x;
  if (t < 16) hl[t] = 0;
  __syncthreads();
  float mn = funkey(mmk[0]), mx = funkey(mmk[1]);
  float rng = fmaxf(mx - mn, 1e-12f);
  const long total = (long)FFUNC*FFUNC;
  for (long idx = (long)blockIdx.x*256 + t; idx < total; idx += (long)gridDim.x*256){
    float v = sc[idx];
    int b = (int)floorf((v - mn)/rng * 16.0f);
    b = min(max(b,0),15);
    atomicAdd(&hl[b], 1u);
  }
  __syncthreads();
  if (t < 16) atomicAdd(&hist[t], hl[t]);
}

// ---------------- final head ----------------
__global__ __launch_bounds__(256) void final_k(
    const float* __restrict__ p1, const float* __restrict__ p2,
    const float* __restrict__ Wtn, const float* __restrict__ Vtn,
    const float* __restrict__ btn, const unsigned* __restrict__ hist,
    const float* __restrict__ Wfc1, const float* __restrict__ bfc1,
    const float* __restrict__ Wsc, const float* __restrict__ bsc,
    float* __restrict__ outp)
{
  __shared__ float P1[128], P2[128], part[256], feats[32], hv[16];
  int t = threadIdx.x;
  if (t < 128){ P1[t] = p1[t]; P2[t] = p2[t]; }
  __syncthreads();
  int k = t & 15, pr_ = t >> 4;
  float acc = 0;
  for (int i = pr_*8; i < pr_*8+8; ++i){
    float pi = P1[i];
    const float* wrow = Wtn + ((size_t)i*128)*16 + k;
    float a2 = 0;
    for (int j=0;j<128;++j) a2 += P2[j]*wrow[(size_t)j*16];
    acc += pi*a2;
  }
  part[t] = acc;
  __syncthreads();
  if (t < 16){
    float sc_ = 0;
    for (int p=0;p<16;p++) sc_ += part[p*16 + t];
    float bl = btn[t];
    for (int j=0;j<256;j++) bl += Vtn[(size_t)t*256 + j] * (j<128 ? P1[j] : P2[j-128]);
    float tv = sc_ + bl;
    feats[t] = tv > 0.f ? tv : 0.f;
    feats[16+t] = (float)hist[t] * (1.0f/((float)FFUNC*(float)FFUNC));
  }
  __syncthreads();
  if (t < 16){
    float a2 = bfc1[t];
    for (int q2=0;q2<32;q2++) a2 += feats[q2]*Wfc1[q2*16 + t];
    hv[t] = a2 > 0.f ? a2 : 0.f;
  }
  __syncthreads();
  if (t == 0){
    float z = bsc[0];
    for (int m=0;m<16;m++) z += hv[m]*Wsc[m];
    outp[0] = sigf(z);
  }
}

// ---------------- host ----------------
extern "C" void kernel_launch(void* const* d_in, const int* in_sizes, int n_in,
                              void* d_out, int out_size, void* d_ws, size_t ws_size,
                              hipStream_t stream)
{
  (void)n_in; (void)out_size; (void)ws_size;
  const float* Wk = (const float*)d_in[16];
  const float* bk = (const float*)d_in[17];
  const float* Wq = (const float*)d_in[18];
  const float* bq = (const float*)d_in[19];
  const float* Wv = (const float*)d_in[20];
  const float* bv = (const float*)d_in[21];
  const float* Wa = (const float*)d_in[22];
  const float* ba = (const float*)d_in[23];
  const float* SKp = (const float*)d_in[24];
  const float* AR = (const float*)d_in[25];
  const float* MRm = (const float*)d_in[26];
  const float* PRp = (const float*)d_in[27];
  const float* WATT = (const float*)d_in[28];
  const float* WTN = (const float*)d_in[29];
  const float* VTN = (const float*)d_in[30];
  const float* BTN = (const float*)d_in[31];
  const float* WFC1 = (const float*)d_in[32];
  const float* BFC1 = (const float*)d_in[33];
  const float* WSC = (const float*)d_in[34];
  const float* BSC = (const float*)d_in[35];

  int NdA[2] = { in_sizes[0]/128, in_sizes[8]/128 };
  int NiA[2] = { in_sizes[1]/128, in_sizes[9]/128 };
  int EA[2][4];
  for (int g=0; g<2; g++)
    for (int r=0; r<4; r++) EA[g][r] = in_sizes[g*8+2+r]/2;

  int NdM = NdA[0] > NdA[1] ? NdA[0] : NdA[1];
  int NiM = NiA[0] > NiA[1] ? NiA[0] : NiA[1];
  long EtotM = 0;
  for (int g=0; g<2; g++){
    long et = 0; for (int r=0;r<4;r++) et += EA[g][r];
    if (et > EtotM) EtotM = et;
  }
  size_t nrowsM = (size_t)NdM + (size_t)NiM;
  int NOR = (int)(((nrowsM + 2 + 63)/64)*64);
  long KR4rows = 3L*NiM + NdM;

  char* wp = (char*)d_ws;
  auto alloc = [&](size_t bytes)->void*{
    void* p = (void*)wp;
    wp += (bytes + 255) & ~(size_t)255;
    return p;
  };
  unsigned short* Xb   = (unsigned short*)alloc(nrowsM*128*2);
  unsigned short* AGG0 = (unsigned short*)alloc(nrowsM*128*2);
  unsigned short* AGG1 = (unsigned short*)alloc(nrowsM*128*2);
  float*          DEN0 = (float*)alloc(nrowsM*4*4);
  float*          DEN1 = (float*)alloc(nrowsM*4*4);
  unsigned short* Qb   = (unsigned short*)alloc(nrowsM*128*2);
  unsigned char*  KRK8 = (unsigned char*)alloc((size_t)KR4rows*128);
  unsigned char*  KRV8 = (unsigned char*)alloc((size_t)KR4rows*128);
  int*            OFFS3= (int*)alloc((size_t)3*NOR*4);   // dir0, dir1, func
  int*            PERM = (int*)alloc((size_t)2*EtotM*4);
  int*            FPERM= (int*)alloc(nrowsM*4);
  int*            PART = (int*)alloc((size_t)3*1024*4);
  float*          GS[2];
  GS[0] = (float*)alloc((size_t)257280*4);
  GS[1] = (float*)alloc((size_t)257280*4);
  unsigned short* FB[2];
  FB[0] = (unsigned short*)alloc((size_t)FFUNC*128*2);
  FB[1] = (unsigned short*)alloc((size_t)FFUNC*128*2);
  unsigned*       MM   = (unsigned*)alloc(2*4);
  unsigned*       HIST = (unsigned*)alloc(16*4);
  unsigned short* WKP  = (unsigned short*)alloc((size_t)8*16384*2);
  unsigned short* WQP  = (unsigned short*)alloc((size_t)8*16384*2);
  unsigned short* WVP  = (unsigned short*)alloc((size_t)8*16384*2);
  unsigned short* WAP  = (unsigned short*)alloc((size_t)8*16384*2);
  unsigned short* WATTP= (unsigned short*)alloc((size_t)16384*2);
  unsigned short* ARP  = (unsigned short*)alloc((size_t)16*4096*2);
  unsigned short* MRP  = (unsigned short*)alloc((size_t)16*4096*2);
  size_t uni_bytes = (size_t)FFUNC*FFUNC*4;
  size_t curs_bytes = (size_t)3*NOR*4;
  void* UNI = alloc(uni_bytes > curs_bytes ? uni_bytes : curs_bytes);
  int*   CURS3 = (int*)UNI;
  float* SCb   = (float*)UNI;

  packw_k<<<8,256,0,stream>>>(Wk, WKP);
  packw_k<<<8,256,0,stream>>>(Wq, WQP);
  packw_k<<<8,256,0,stream>>>(Wv, WVP);
  packw_k<<<8,256,0,stream>>>(Wa, WAP);
  packw_k<<<1,256,0,stream>>>(WATT, WATTP);
  packa_k<<<16,256,0,stream>>>(AR, ARP);
  packa_k<<<16,256,0,stream>>>(MRm, MRP);

  const size_t OF_FSUM=0, OF_FCNT=128000, OF_CF=129024, OF_ATTC=257024, OF_POOL=257152;
  const int stf[4] = {1,0,1,1};
  const int dtf[4] = {1,1,0,1};

  for (int g=0; g<2; ++g){
    int nd = NdA[g], ni = NiA[g];
    int nrows = nd + ni;
    int E[4] = {EA[g][0],EA[g][1],EA[g][2],EA[g][3]};
    const int* ei[4] = {(const int*)d_in[g*8+2], (const int*)d_in[g*8+3],
                        (const int*)d_in[g*8+4], (const int*)d_in[g*8+5]};
    const int* fdp = (const int*)d_in[g*8+6];
    const int* fip = (const int*)d_in[g*8+7];
    const float* x0d = (const float*)d_in[g*8+0];
    const float* x0i = (const float*)d_in[g*8+1];
    int gbd = (nd+63)/64, gbi = (ni+63)/64;
    int nb = gbd + gbi;
    int ntb = (nrows+255)/256; if (ntb > 2048) ntb = 2048;

    int koff[2][4], stA[2][4], dtA[2][4];
    for (int c=0;c<2;c++){
      int run = 0;
      for (int r=0;r<4;r++){
        stA[c][r] = (c==0) ? stf[r] : dtf[r];
        dtA[c][r] = (c==0) ? dtf[r] : stf[r];
        koff[c][r] = run;
        run += stA[c][r] ? ni : nd;
      }
    }

    // ---- build 2 merged edge CSRs + function CSR ----
    hipMemsetAsync(OFFS3, 0, (size_t)3*NOR*4, stream);
    HD hd; int hb = 0;
    for (int c2=0; c2<2; c2++)
      for (int r=0; r<4; r++){
        int ent = c2*4 + r;
        hd.blk0[ent] = hb;
        hd.dst[ent] = (c2==0) ? ei[r]+E[r] : ei[r];
        hd.src[ent] = (c2==0) ? ei[r] : ei[r]+E[r];
        hd.E[ent] = E[r];
        hd.cnto[ent] = c2*NOR + (dtA[c2][r] ? nd : 0);
        hd.permo[ent] = c2*(int)EtotM;
        hb += (E[r]+255)/256;
      }
    hd.blk0[8] = hb;
    csr_hist_all_k<<<hb,256,0,stream>>>(hd, OFFS3);
    fhist_k<<<ntb,256,0,stream>>>(fdp, fip, nd, ni, OFFS3 + (size_t)2*NOR);
    ScanDesc sd; sd.n[0] = nrows; sd.n[1] = nrows; sd.n[2] = FFUNC;
    int maxtiles = (nrows + 1023)/1024; if (maxtiles < 1) maxtiles = 1;
    dim3 sgrid(maxtiles, 3);
    scan_p1<<<sgrid,1024,0,stream>>>(sd, OFFS3, PART, NOR, maxtiles);
    scan_p2<<<1,1024,0,stream>>>(PART, maxtiles, 3);
    scan_p3<<<sgrid,1024,0,stream>>>(sd, OFFS3, CURS3, PART, NOR, maxtiles);
    csr_fill_all_k<<<hb,256,0,stream>>>(hd, CURS3, PERM);
    ffill_k<<<ntb,256,0,stream>>>(fdp, fip, nd, ni, CURS3 + (size_t)2*NOR, FPERM);

    for (int l=0; l<2; ++l){
      const void* xd = (l==0) ? (const void*)x0d : (const void*)Xb;
      const void* xi = (l==0) ? (const void*)x0i : (const void*)(Xb + (size_t)nd*128);
      int af32 = (l==0);
      for (int c=0; c<2; ++c){
        int pc = l*2 + c;
        KX kx;
        for (int r=0;r<4;r++){ kx.styp[r] = stA[c][r]; kx.koff[r] = koff[c][r]; }
        gemm_kqvx_k<<<nb,256,0,stream>>>(
            xd, xi, af32, nd, ni, gbd,
            WKP+(size_t)pc*2*16384, WQP+(size_t)pc*2*16384, WVP+(size_t)pc*2*16384,
            bk+(size_t)pc*2*128, bq+(size_t)pc*2*128, bv+(size_t)pc*2*128,
            ARP + (size_t)pc*4*4096, MRP + (size_t)pc*4*4096,
            Qb, KRK8, KRV8, kx);
        MD md;
        for (int r=0;r<4;r++) md.koff[r] = koff[c][r];
        int eblk = (nrows*32 + 255)/256;
        e12m_k<<<eblk,256,0,stream>>>(KRK8, KRV8, Qb,
                                      OFFS3 + (size_t)c*NOR, PERM + (size_t)c*EtotM, nrows,
                                      PRp + (size_t)pc*16,
                                      (c==0) ? AGG0 : AGG1,
                                      (c==0) ? DEN0 : DEN1, md);
      }
      // fused both-direction epilogue -> Xb (no O1b)
      gemm_epi2_k<<<nb,256,0,stream>>>(
          AGG0, DEN0, AGG1, DEN1, nd, ni, gbd,
          WAP + (size_t)l*4*16384, ba + (size_t)l*4*128,
          xd, xi, af32, Xb, SKp + (size_t)l*4);
    }
    // pooling (function-CSR, bf16 X)
    float* fsum = GS[g]+OF_FSUM;  float* fcnt = GS[g]+OF_FCNT;
    float* cf   = GS[g]+OF_CF;    float* attc = GS[g]+OF_ATTC;
    float* pool = GS[g]+OF_POOL;
    hipMemsetAsync(pool, 0, 128*4, stream);
    f1c_k<<<FFUNC,256,0,stream>>>(Xb, OFFS3 + (size_t)2*NOR, FPERM, fsum, fcnt);
    attc2_k<<<1,1024,0,stream>>>(fsum, 1.0f/(float)nrows, WATT, attc);
    gemmb_k<<<(FFUNC+63)/64,256,0,stream>>>(fsum, FFUNC, WATTP, nullptr, cf, 1, fcnt);
    f23c_k<<<FFUNC,256,0,stream>>>(Xb, OFFS3 + (size_t)2*NOR, FPERM, cf, attc, FB[g], pool);
  }
  // similarity histogram + final head
  hist_init_k<<<1,32,0,stream>>>(MM, HIST);
  dim3 gnt((FFUNC+63)/64, (FFUNC+63)/64);
  gemmnt_b<<<gnt,256,0,stream>>>(FB[0], FB[1], SCb, MM);
  hist_k<<<512,256,0,stream>>>(SCb, MM, HIST);
  final_k<<<1,256,0,stream>>>(GS[0]+OF_POOL, GS[1]+OF_POOL, WTN, VTN, BTN, HIST,
                              WFC1, BFC1, WSC, BSC, (float*)d_out);
}

// Round 14
// 1795.100 us; speedup vs baseline: 1.0891x; 1.0891x over previous
//
#include <hip/hip_runtime.h>
#include <math.h>

#define FFUNC 1000

typedef __attribute__((ext_vector_type(8))) short s8v;
typedef __attribute__((ext_vector_type(4))) float f4v;

// ---------------- device helpers ----------------
__device__ __forceinline__ float sigf(float x){ return 1.0f/(1.0f+__expf(-x)); }
// gelu(tanh approx): 0.5x(1+tanh(u)) == x*sigmoid(2u)
__device__ __forceinline__ float geluf(float x){
  float u = 1.5957691216057308f * (x + 0.044715f*x*x*x);
  return x / (1.0f + __expf(-u));
}
__device__ __forceinline__ unsigned fkey(float f){
  unsigned u = __float_as_uint(f);
  return (u & 0x80000000u) ? ~u : (u | 0x80000000u);
}
__device__ __forceinline__ float funkey(unsigned k){
  unsigned u = (k & 0x80000000u) ? (k ^ 0x80000000u) : ~k;
  return __uint_as_float(u);
}
__device__ __forceinline__ void atomAddF(float* p, float v){ unsafeAtomicAdd(p, v); }
__device__ __forceinline__ unsigned short bfr(float x){   // f32 -> bf16 RNE
  unsigned u = __float_as_uint(x);
  unsigned r = (u + 0x7FFFu + ((u >> 16) & 1u)) >> 16;
  return (unsigned short)r;
}
__device__ __forceinline__ float b2f(unsigned short v){
  return __uint_as_float((unsigned)v << 16);
}

// ---------------- weight prepack ----------------
__global__ void packw_k(const float* __restrict__ W, unsigned short* __restrict__ out){
  int mat = blockIdx.x;
  const float* w = W + (size_t)mat*16384;
  unsigned short* o = out + (size_t)mat*16384;
  for (int u=0; u<64; u++){
    int oi = u*256 + threadIdx.x;
    int j = oi & 7, l = (oi>>3) & 63, nt = (oi>>9) & 7, kt = oi >> 12;
    float v = w[(size_t)(kt*32 + 8*(l>>4) + j)*128 + nt*16 + (l&15)];
    o[oi] = bfr(v);
  }
}

__global__ void packa_k(const float* __restrict__ A, unsigned short* __restrict__ out){
  int ent = blockIdx.x;
  const float* a = A + (size_t)ent*4096;
  unsigned short* o = out + (size_t)ent*4096;
  for (int u=0; u<16; u++){
    int oi = u*256 + threadIdx.x;
    int j = oi & 7, l = (oi>>3) & 63, nt = (oi>>9) & 1, h = oi >> 10;
    float v = a[(size_t)h*1024 + (size_t)(8*(l>>4)+j)*32 + nt*16 + (l&15)];
    o[oi] = bfr(v);
  }
}

// ---------------- fused K/Q/V projection + per-relation transforms ----------------
// All outputs staged via swizzled LDS tile -> coalesced 16B stores.
struct KX { int styp[4]; int koff[4]; };
__global__ __launch_bounds__(256) void gemm_kqvx_k(
    const void* __restrict__ xdv, const void* __restrict__ xiv, int af32,
    int nd, int ni, int gbd,
    const unsigned short* __restrict__ WK, const unsigned short* __restrict__ WQ,
    const unsigned short* __restrict__ WV,
    const float* __restrict__ bK, const float* __restrict__ bQ, const float* __restrict__ bV,
    const unsigned short* __restrict__ ARpc, const unsigned short* __restrict__ MRpc,
    unsigned short* __restrict__ Qb,
    unsigned short* __restrict__ KRK, unsigned short* __restrict__ KRV, KX kx)
{
  __shared__ __align__(16) unsigned short tile[64*128];
  int blk = blockIdx.x;
  int ty = (blk >= gbd);
  int N = ty ? ni : nd;
  int rbase = (ty ? (blk - gbd) : blk) * 64;
  size_t obase = ty ? (size_t)nd*128 : 0;
  const unsigned short* wk = WK + (ty ? 16384 : 0);
  const unsigned short* wq = WQ + (ty ? 16384 : 0);
  const unsigned short* wv = WV + (ty ? 16384 : 0);
  const float* bk2 = bK + (ty ? 128 : 0);
  const float* bq2 = bQ + (ty ? 128 : 0);
  const float* bv2 = bV + (ty ? 128 : 0);
  const float* Af = (const float*)(ty ? xiv : xdv);
  const unsigned short* Ab = (const unsigned short*)(ty ? xiv : xdv);

  int t = threadIdx.x;
  int l = t & 63, w = t >> 6, b = l >> 4, m = l & 15;
  int arow = rbase + w*16 + m;
  bool rv = arow < N;
  int lrow = w*16 + m;

  // input A-fragments (held across all three matrices)
  s8v axf[4];
  #pragma unroll
  for (int kt=0; kt<4; kt++){
    s8v af = (s8v){0,0,0,0,0,0,0,0};
    if (rv){
      if (af32){
        const float* ap = Af + (size_t)arow*128 + kt*32 + b*8;
        float4 x0 = *(const float4*)ap;
        float4 x1 = *(const float4*)(ap + 4);
        af[0]=(short)bfr(x0.x); af[1]=(short)bfr(x0.y); af[2]=(short)bfr(x0.z); af[3]=(short)bfr(x0.w);
        af[4]=(short)bfr(x1.x); af[5]=(short)bfr(x1.y); af[6]=(short)bfr(x1.z); af[7]=(short)bfr(x1.w);
      } else {
        af = *(const s8v*)(Ab + (size_t)arow*128 + kt*32 + b*8);
      }
    }
    axf[kt] = af;
  }

  f4v acc[8];
  // ================= Q =================
  #pragma unroll
  for (int nt=0; nt<8; nt++) acc[nt] = (f4v){0,0,0,0};
  #pragma unroll
  for (int kt=0; kt<4; kt++)
    #pragma unroll
    for (int nt=0; nt<8; nt++){
      s8v bf = *(const s8v*)(wq + ((kt*8 + nt)*64 + l)*8);
      acc[nt] = __builtin_amdgcn_mfma_f32_16x16x32_bf16(axf[kt], bf, acc[nt], 0, 0, 0);
    }
  #pragma unroll
  for (int r2=0; r2<4; r2++){
    int trow = w*16 + 4*b + r2;
    #pragma unroll
    for (int nt=0; nt<8; nt++){
      int col = nt*16 + m;
      int ch = (col>>3) ^ (trow&15);
      tile[trow*128 + ch*8 + (col&7)] = bfr(acc[nt][r2] + bq2[col]);
    }
  }
  __syncthreads();
  #pragma unroll
  for (int it=0; it<4; it++){
    int idx = it*256 + t;
    int rr = idx >> 4, cc = idx & 15;
    int orow = rbase + rr;
    if (orow < N)
      *(uint4*)(Qb + obase + (size_t)orow*128 + cc*8) =
          *(const uint4*)(&tile[rr*128 + ((cc ^ (rr&15))*8)]);
  }
  __syncthreads();

  // ================= K -> transform -> KRK =================
  #pragma unroll
  for (int nt=0; nt<8; nt++) acc[nt] = (f4v){0,0,0,0};
  #pragma unroll
  for (int kt=0; kt<4; kt++)
    #pragma unroll
    for (int nt=0; nt<8; nt++){
      s8v bf = *(const s8v*)(wk + ((kt*8 + nt)*64 + l)*8);
      acc[nt] = __builtin_amdgcn_mfma_f32_16x16x32_bf16(axf[kt], bf, acc[nt], 0, 0, 0);
    }
  #pragma unroll
  for (int r2=0; r2<4; r2++){
    int trow = w*16 + 4*b + r2;
    #pragma unroll
    for (int nt=0; nt<8; nt++){
      int col = nt*16 + m;
      int ch = (col>>3) ^ (trow&15);
      tile[trow*128 + ch*8 + (col&7)] = bfr(acc[nt][r2] + bk2[col]);
    }
  }
  __syncthreads();
  {
    s8v kf[4];
    #pragma unroll
    for (int h=0; h<4; h++){
      int ch = (h*4 + b) ^ (lrow&15);
      kf[h] = *(const s8v*)(&tile[lrow*128 + ch*8]);
    }
    __syncthreads();
    #pragma unroll
    for (int r=0; r<4; r++){
      if (kx.styp[r] != ty) continue;
      const unsigned short* Ap = ARpc + r*4096;
      f4v xa[8];
      #pragma unroll
      for (int i=0;i<8;i++) xa[i] = (f4v){0,0,0,0};
      #pragma unroll
      for (int h=0; h<4; h++)
        #pragma unroll
        for (int n2=0; n2<2; n2++){
          s8v bf = *(const s8v*)(Ap + ((h*2 + n2)*64 + l)*8);
          xa[h*2+n2] = __builtin_amdgcn_mfma_f32_16x16x32_bf16(kf[h], bf, xa[h*2+n2], 0, 0, 0);
        }
      #pragma unroll
      for (int r2=0; r2<4; r2++){
        int trow = w*16 + 4*b + r2;
        #pragma unroll
        for (int h=0; h<4; h++)
          #pragma unroll
          for (int n2=0; n2<2; n2++){
            int col = h*32 + n2*16 + m;
            int ch = (col>>3) ^ (trow&15);
            tile[trow*128 + ch*8 + (col&7)] = bfr(xa[h*2+n2][r2]);
          }
      }
      __syncthreads();
      int ko = kx.koff[r];
      #pragma unroll
      for (int it=0; it<4; it++){
        int idx = it*256 + t;
        int rr = idx >> 4, cc = idx & 15;
        int orow = rbase + rr;
        if (orow < N)
          *(uint4*)(KRK + (size_t)(ko + orow)*128 + cc*8) =
              *(const uint4*)(&tile[rr*128 + ((cc ^ (rr&15))*8)]);
      }
      __syncthreads();
    }
  }

  // ================= V -> transform -> KRV =================
  #pragma unroll
  for (int nt=0; nt<8; nt++) acc[nt] = (f4v){0,0,0,0};
  #pragma unroll
  for (int kt=0; kt<4; kt++)
    #pragma unroll
    for (int nt=0; nt<8; nt++){
      s8v bf = *(const s8v*)(wv + ((kt*8 + nt)*64 + l)*8);
      acc[nt] = __builtin_amdgcn_mfma_f32_16x16x32_bf16(axf[kt], bf, acc[nt], 0, 0, 0);
    }
  #pragma unroll
  for (int r2=0; r2<4; r2++){
    int trow = w*16 + 4*b + r2;
    #pragma unroll
    for (int nt=0; nt<8; nt++){
      int col = nt*16 + m;
      int ch = (col>>3) ^ (trow&15);
      tile[trow*128 + ch*8 + (col&7)] = bfr(acc[nt][r2] + bv2[col]);
    }
  }
  __syncthreads();
  {
    s8v vf[4];
    #pragma unroll
    for (int h=0; h<4; h++){
      int ch = (h*4 + b) ^ (lrow&15);
      vf[h] = *(const s8v*)(&tile[lrow*128 + ch*8]);
    }
    __syncthreads();
    #pragma unroll
    for (int r=0; r<4; r++){
      if (kx.styp[r] != ty) continue;
      const unsigned short* Ap = MRpc + r*4096;
      f4v xa[8];
      #pragma unroll
      for (int i=0;i<8;i++) xa[i] = (f4v){0,0,0,0};
      #pragma unroll
      for (int h=0; h<4; h++)
        #pragma unroll
        for (int n2=0; n2<2; n2++){
          s8v bf = *(const s8v*)(Ap + ((h*2 + n2)*64 + l)*8);
          xa[h*2+n2] = __builtin_amdgcn_mfma_f32_16x16x32_bf16(vf[h], bf, xa[h*2+n2], 0, 0, 0);
        }
      #pragma unroll
      for (int r2=0; r2<4; r2++){
        int trow = w*16 + 4*b + r2;
        #pragma unroll
        for (int h=0; h<4; h++)
          #pragma unroll
          for (int n2=0; n2<2; n2++){
            int col = h*32 + n2*16 + m;
            int ch = (col>>3) ^ (trow&15);
            tile[trow*128 + ch*8 + (col&7)] = bfr(xa[h*2+n2][r2]);
          }
      }
      __syncthreads();
      int ko = kx.koff[r];
      #pragma unroll
      for (int it=0; it<4; it++){
        int idx = it*256 + t;
        int rr = idx >> 4, cc = idx & 15;
        int orow = rbase + rr;
        if (orow < N)
          *(uint4*)(KRV + (size_t)(ko + orow)*128 + cc*8) =
              *(const uint4*)(&tile[rr*128 + ((cc ^ (rr&15))*8)]);
      }
      __syncthreads();
    }
  }
}

// ---------------- fused epilogue GEMM (LDS-staged wide epilogue) ----------------
__global__ __launch_bounds__(256) void gemm_epi_k(
    const unsigned short* __restrict__ AGGb, const float* __restrict__ DENb,
    int nd, int ni, int gbd,
    const unsigned short* __restrict__ WA, const float* __restrict__ bA,
    const void* __restrict__ xin_dv, const void* __restrict__ xin_iv, int xf32,
    const unsigned short* __restrict__ o1p, unsigned short* __restrict__ out,
    const float* __restrict__ skp, int mode)
{
  __shared__ __align__(16) float ftile[64*128];
  int blk = blockIdx.x;
  int ty = (blk >= gbd);
  int N = ty ? ni : nd;
  int rbase = (ty ? (blk - gbd) : blk) * 64;
  int goff = ty ? nd : 0;
  const unsigned short* wa = WA + (ty ? 16384 : 0);
  const float* ba2 = bA + (ty ? 128 : 0);
  const float* xinF = (const float*)(ty ? xin_iv : xin_dv);
  const unsigned short* xinB = (const unsigned short*)(ty ? xin_iv : xin_dv);
  float s = sigf(skp[ty]), s1 = 1.0f - s;

  int t = threadIdx.x;
  int l = t & 63, w = t >> 6, b = l >> 4, m = l & 15;
  int arow = rbase + w*16 + m;
  bool rv = arow < N;
  f4v acc[8];
  #pragma unroll
  for (int nt=0; nt<8; nt++) acc[nt] = (f4v){0,0,0,0};

  float4 dv4 = make_float4(1.f,1.f,1.f,1.f);
  if (rv){
    size_t grow = (size_t)(goff + arow);
    float4 dr = *(const float4*)(DENb + grow*4);
    dv4.x = 1.0f / fmaxf(dr.x, 1e-16f);
    dv4.y = 1.0f / fmaxf(dr.y, 1e-16f);
    dv4.z = 1.0f / fmaxf(dr.z, 1e-16f);
    dv4.w = 1.0f / fmaxf(dr.w, 1e-16f);
  }
  #pragma unroll
  for (int kt=0; kt<4; kt++){
    s8v af = (s8v){0,0,0,0,0,0,0,0};
    if (rv){
      size_t grow = (size_t)(goff + arow);
      float dv = (kt==0)?dv4.x:(kt==1)?dv4.y:(kt==2)?dv4.z:dv4.w;
      s8v ag = *(const s8v*)(AGGb + grow*128 + kt*32 + b*8);
      #pragma unroll
      for (int jj=0; jj<8; jj++)
        af[jj] = (short)bfr(geluf(b2f((unsigned short)ag[jj]) * dv));
    }
    #pragma unroll
    for (int nt=0; nt<8; nt++){
      s8v bf = *(const s8v*)(wa + ((kt*8 + nt)*64 + l)*8);
      acc[nt] = __builtin_amdgcn_mfma_f32_16x16x32_bf16(af, bf, acc[nt], 0, 0, 0);
    }
  }
  // stage f32 acc into swizzled tile
  #pragma unroll
  for (int r2=0; r2<4; r2++){
    int trow = w*16 + 4*b + r2;
    #pragma unroll
    for (int nt=0; nt<8; nt++){
      int col = nt*16 + m;
      int ch = (col>>2) ^ (trow&31);
      ftile[trow*128 + ch*4 + (col&3)] = acc[nt][r2];
    }
  }
  __syncthreads();
  // wide epilogue: bias + skip (+combine) + store
  #pragma unroll
  for (int it=0; it<8; it++){
    int idx = it*256 + t;          // row*32 + chunk
    int rr = idx >> 5, cc = idx & 31;
    int orow = rbase + rr;
    if (orow >= N) continue;
    size_t grow = (size_t)(goff + orow);
    float4 a4 = *(const float4*)(&ftile[rr*128 + ((cc ^ (rr&31))*4)]);
    float4 b4 = *(const float4*)(ba2 + cc*4);
    float xv0, xv1, xv2, xv3;
    if (xf32){
      float4 x4 = *(const float4*)(xinF + (size_t)orow*128 + cc*4);
      xv0=x4.x; xv1=x4.y; xv2=x4.z; xv3=x4.w;
    } else {
      ushort4 x4 = *(const ushort4*)(xinB + (size_t)orow*128 + cc*4);
      xv0=b2f(x4.x); xv1=b2f(x4.y); xv2=b2f(x4.z); xv3=b2f(x4.w);
    }
    float v0 = s*(a4.x + b4.x) + s1*xv0;
    float v1 = s*(a4.y + b4.y) + s1*xv1;
    float v2 = s*(a4.z + b4.z) + s1*xv2;
    float v3 = s*(a4.w + b4.w) + s1*xv3;
    if (mode == 3){
      ushort4 o4 = *(const ushort4*)(o1p + grow*128 + cc*4);
      v0 = fmaxf(0.5f*b2f(o4.x) + 0.5f*v0, 0.f);
      v1 = fmaxf(0.5f*b2f(o4.y) + 0.5f*v1, 0.f);
      v2 = fmaxf(0.5f*b2f(o4.z) + 0.5f*v2, 0.f);
      v3 = fmaxf(0.5f*b2f(o4.w) + 0.5f*v3, 0.f);
    }
    *(ushort4*)(out + grow*128 + cc*4) =
        make_ushort4(bfr(v0), bfr(v1), bfr(v2), bfr(v3));
  }
}

// ---------------- merged CSR build ----------------
struct ScanDesc { int n[8]; };

struct HD {
  int blk0[9];
  const int* dst[8];
  const int* src[8];
  int E[8];
  int cnto[8];
  int permo[8];
};
__global__ void csr_hist_all_k(HD d, int* __restrict__ cnt){
  int b = blockIdx.x;
  int r = 0;
  while (r < 7 && b >= d.blk0[r+1]) r++;
  int e = (b - d.blk0[r])*256 + threadIdx.x;
  if (e < d.E[r]) atomicAdd(&cnt[d.cnto[r] + d.dst[r][e]], 1);
}
__global__ void csr_fill_all_k(HD d, int* __restrict__ curs, int* __restrict__ perm){
  int b = blockIdx.x;
  int r = 0;
  while (r < 7 && b >= d.blk0[r+1]) r++;
  int e = (b - d.blk0[r])*256 + threadIdx.x;
  if (e < d.E[r]){
    int pos = atomicAdd(&curs[d.cnto[r] + d.dst[r][e]], 1);
    perm[d.permo[r] + pos] = d.src[r][e] | ((r & 3) << 24);
  }
}

// ---------------- parallel 3-phase scan ----------------
__global__ __launch_bounds__(1024) void scan_p1(ScanDesc sd, const int* __restrict__ offs,
                                                int* __restrict__ part, int NO, int MAXT){
  int ent = blockIdx.y, tile = blockIdx.x;
  int n = sd.n[ent];
  int i = tile*1024 + threadIdx.x;
  int v = (i < n) ? offs[(size_t)ent*NO + i] : 0;
  #pragma unroll
  for (int d2=1; d2<64; d2<<=1) v += __shfl_xor(v, d2, 64);
  __shared__ int ws_[16];
  int lane = threadIdx.x & 63, wv = threadIdx.x >> 6;
  if (lane == 0) ws_[wv] = v;
  __syncthreads();
  if (threadIdx.x == 0){
    int s = 0;
    #pragma unroll
    for (int k=0;k<16;k++) s += ws_[k];
    part[ent*MAXT + tile] = s;
  }
}

__global__ __launch_bounds__(1024) void scan_p2(int* __restrict__ part, int MAXT, int nent){
  int tid = threadIdx.x, lane = tid & 63, wv = tid >> 6;
  __shared__ int wsum[16];
  __shared__ int woff[17];
  for (int ent=0; ent<nent; ent++){
    int v = (tid < MAXT) ? part[ent*MAXT + tid] : 0;
    int s = v;
    #pragma unroll
    for (int d2=1; d2<64; d2<<=1){
      int t2 = __shfl_up(s, d2, 64);
      if (lane >= d2) s += t2;
    }
    if (lane == 63) wsum[wv] = s;
    __syncthreads();
    if (wv == 0 && lane < 16){
      int x = wsum[lane];
      #pragma unroll
      for (int d2=1; d2<16; d2<<=1){
        int t2 = __shfl_up(x, d2, 64);
        if (lane >= d2) x += t2;
      }
      woff[lane+1] = x;
      if (lane == 0) woff[0] = 0;
    }
    __syncthreads();
    if (tid < MAXT) part[ent*MAXT + tid] = woff[wv] + s - v;
    __syncthreads();
  }
}

__global__ __launch_bounds__(1024) void scan_p3(ScanDesc sd, int* __restrict__ offs,
                                                int* __restrict__ curs,
                                                const int* __restrict__ part, int NO, int MAXT){
  int ent = blockIdx.y, tile = blockIdx.x;
  int n = sd.n[ent];
  int i = tile*1024 + threadIdx.x;
  int v = (i < n) ? offs[(size_t)ent*NO + i] : 0;
  int lane = threadIdx.x & 63, wv = threadIdx.x >> 6;
  int s = v;
  #pragma unroll
  for (int d2=1; d2<64; d2<<=1){
    int t2 = __shfl_up(s, d2, 64);
    if (lane >= d2) s += t2;
  }
  __shared__ int wsum[16];
  __shared__ int woff[17];
  if (lane == 63) wsum[wv] = s;
  __syncthreads();
  if (wv == 0 && lane < 16){
    int x = wsum[lane];
    #pragma unroll
    for (int d2=1; d2<16; d2<<=1){
      int t2 = __shfl_up(x, d2, 64);
      if (lane >= d2) x += t2;
    }
    woff[lane+1] = x;
    if (lane == 0) woff[0] = 0;
  }
  __syncthreads();
  int excl = part[ent*MAXT + tile] + woff[wv] + s - v;
  if (i < n){
    offs[(size_t)ent*NO + i] = excl;
    curs[(size_t)ent*NO + i] = excl;
  }
  if (i == n-1) offs[(size_t)ent*NO + n] = excl + v;
}

// ---------------- function-CSR build ----------------
__global__ void fhist_k(const int* __restrict__ fd, const int* __restrict__ fi,
                        int Nd, int Ni, int* __restrict__ cnt){
  int nt = Nd + Ni;
  for (int n = blockIdx.x*256 + threadIdx.x; n < nt; n += gridDim.x*256){
    int f = (n < Nd) ? fd[n] : fi[n-Nd];
    atomicAdd(&cnt[f], 1);
  }
}
__global__ void ffill_k(const int* __restrict__ fd, const int* __restrict__ fi,
                        int Nd, int Ni, int* __restrict__ curs, int* __restrict__ perm){
  int nt = Nd + Ni;
  for (int n = blockIdx.x*256 + threadIdx.x; n < nt; n += gridDim.x*256){
    int f = (n < Nd) ? fd[n] : fi[n-Nd];
    int pos = atomicAdd(&curs[f], 1);
    perm[pos] = n;
  }
}

// ---------------- E12 merged: online-softmax edge aggregation ----------------
struct MD { int koff[4]; };
__global__ __launch_bounds__(256) void e12m_k(
    const unsigned short* __restrict__ KRK, const unsigned short* __restrict__ KRV,
    const unsigned short* __restrict__ Qb,
    const int* __restrict__ offs, const int* __restrict__ perm, int nrows,
    const float* __restrict__ pr,
    unsigned short* __restrict__ aggb, float* __restrict__ den, MD md)
{
  int gidx = blockIdx.x*256 + threadIdx.x;
  int node = gidx >> 5; if (node >= nrows) return;
  int sub = gidx & 31, h = sub >> 3, j = sub & 7;
  int o0 = offs[node], o1 = offs[node+1];
  unsigned short* ap = aggb + (size_t)node*128 + h*32 + j*4;
  if (o0 == o1){
    *(ushort4*)ap = make_ushort4(0,0,0,0);
    if (j == 0) den[(size_t)node*4 + h] = 0.f;
    return;
  }
  ushort4 qa = *(const ushort4*)(Qb + (size_t)node*128 + h*32 + j*4);
  float q0=b2f(qa.x), q1=b2f(qa.y), q2=b2f(qa.z), q3=b2f(qa.w);
  float scl[4];
  #pragma unroll
  for (int r=0;r<4;r++) scl[r] = pr[r*4 + h] * 0.17677669529663687f;  // 1/sqrt(32)
  float mx = -INFINITY, ds = 0.f;
  float4 acc = make_float4(0.f,0.f,0.f,0.f);
  for (int i=o0; i<o1; ++i){
    int pk = perm[i];
    int src = pk & 0xFFFFFF, rel = pk >> 24;
    size_t rowo = (size_t)(md.koff[rel] + src)*128 + h*32 + j*4;
    ushort4 aa = *(const ushort4*)(KRK + rowo);
    ushort4 vv = *(const ushort4*)(KRV + rowo);
    float p = b2f(aa.x)*q0 + b2f(aa.y)*q1 + b2f(aa.z)*q2 + b2f(aa.w)*q3;
    p += __shfl_xor(p, 1, 8);
    p += __shfl_xor(p, 2, 8);
    p += __shfl_xor(p, 4, 8);
    float lg = p * scl[rel];
    float nm = fmaxf(mx, lg);
    float corr = __expf(mx - nm);
    float ev = __expf(lg - nm);
    acc.x = acc.x*corr + ev*b2f(vv.x);
    acc.y = acc.y*corr + ev*b2f(vv.y);
    acc.z = acc.z*corr + ev*b2f(vv.z);
    acc.w = acc.w*corr + ev*b2f(vv.w);
    ds = ds*corr + ev;
    mx = nm;
  }
  *(ushort4*)ap = make_ushort4(bfr(acc.x), bfr(acc.y), bfr(acc.z), bfr(acc.w));
  if (j == 0) den[(size_t)node*4 + h] = ds;
}

// ---------------- plain MFMA GEMM (cf only; optional per-row divide) ----------------
__global__ __launch_bounds__(256) void gemmb_k(
    const float* __restrict__ A, int N,
    const unsigned short* __restrict__ Wp, const float* __restrict__ bias,
    float* __restrict__ outf, int mode, const float* __restrict__ rdiv)
{
  int t = threadIdx.x;
  int l = t & 63, w = t >> 6, b = l >> 4, m = l & 15;
  int arow = blockIdx.x*64 + w*16 + m;
  bool rv = arow < N;
  float dv = 1.0f;
  if (rv && rdiv) dv = 1.0f / fmaxf(rdiv[arow], 1.0f);
  f4v acc[8];
  #pragma unroll
  for (int nt=0; nt<8; nt++) acc[nt] = (f4v){0,0,0,0};
  #pragma unroll
  for (int kt=0; kt<4; kt++){
    s8v af = (s8v){0,0,0,0,0,0,0,0};
    if (rv){
      const float* ap = A + (size_t)arow*128 + kt*32 + b*8;
      float4 x0 = *(const float4*)ap;
      float4 x1 = *(const float4*)(ap + 4);
      af[0]=(short)bfr(x0.x*dv); af[1]=(short)bfr(x0.y*dv); af[2]=(short)bfr(x0.z*dv); af[3]=(short)bfr(x0.w*dv);
      af[4]=(short)bfr(x1.x*dv); af[5]=(short)bfr(x1.y*dv); af[6]=(short)bfr(x1.z*dv); af[7]=(short)bfr(x1.w*dv);
    }
    #pragma unroll
    for (int nt=0; nt<8; nt++){
      s8v bf = *(const s8v*)(Wp + ((kt*8 + nt)*64 + l)*8);
      acc[nt] = __builtin_amdgcn_mfma_f32_16x16x32_bf16(af, bf, acc[nt], 0, 0, 0);
    }
  }
  #pragma unroll
  for (int r2=0; r2<4; r2++){
    int orow = blockIdx.x*64 + w*16 + 4*b + r2;
    if (orow >= N) continue;
    #pragma unroll
    for (int nt=0; nt<8; nt++){
      int col = nt*16 + m;
      float v = acc[nt][r2];
      if (bias) v += bias[col];
      if (mode == 1) v = tanhf(v);
      outf[(size_t)orow*128 + col] = v;
    }
  }
}

// ---------------- func pool (CSR, bf16 X): sums + counts ----------------
__global__ __launch_bounds__(256) void f1c_k(const unsigned short* __restrict__ X,
    const int* __restrict__ foffs, const int* __restrict__ fperm,
    float* __restrict__ fsum, float* __restrict__ fcnt)
{
  __shared__ __align__(16) float red[4][128];
  int t = threadIdx.x, wv = t >> 6, lane = t & 63;
  int f = blockIdx.x;
  int o0 = foffs[f], o1 = foffs[f+1];
  float a0 = 0, a1 = 0;
  for (int i = o0 + wv; i < o1; i += 4){
    ushort2 x = *(const ushort2*)(X + (size_t)fperm[i]*128 + lane*2);
    a0 += b2f(x.x); a1 += b2f(x.y);
  }
  red[wv][lane*2] = a0; red[wv][lane*2+1] = a1;
  __syncthreads();
  if (t < 128)
    fsum[(size_t)f*128 + t] = red[0][t] + red[1][t] + red[2][t] + red[3][t];
  if (t == 0) fcnt[f] = (float)(o1 - o0);
}

// ---------------- func pool (CSR, bf16 X): femb(bf16) + global attention pool ----------------
__global__ __launch_bounds__(256) void f23c_k(const unsigned short* __restrict__ X,
    const int* __restrict__ foffs, const int* __restrict__ fperm,
    const float* __restrict__ cf, const float* __restrict__ attc,
    unsigned short* __restrict__ fembb, float* __restrict__ pooled)
{
  __shared__ __align__(16) float rede[4][128];
  __shared__ __align__(16) float redp[4][128];
  int t = threadIdx.x, wv = t >> 6, lane = t & 63;
  int f = blockIdx.x;
  int o0 = foffs[f], o1 = foffs[f+1];
  float c0 = cf[(size_t)f*128 + lane*2], c1 = cf[(size_t)f*128 + lane*2 + 1];
  float t0 = attc[lane*2], t1 = attc[lane*2 + 1];
  float e0=0, e1=0, p0=0, p1=0;
  for (int i = o0 + wv; i < o1; i += 4){
    ushort2 xr = *(const ushort2*)(X + (size_t)fperm[i]*128 + lane*2);
    float vx = b2f(xr.x), vy = b2f(xr.y);
    union { double d; float2 f2; } u;
    u.f2.x = vx*c0 + vy*c1;
    u.f2.y = vx*t0 + vy*t1;
    #pragma unroll
    for (int m2=1; m2<64; m2<<=1){
      union { double d; float2 f2; } v;
      v.d = __shfl_xor(u.d, m2, 64);
      u.f2.x += v.f2.x; u.f2.y += v.f2.y;
    }
    float s1 = sigf(u.f2.x), s2 = sigf(u.f2.y);
    e0 += vx*s1; e1 += vy*s1;
    p0 += vx*s2; p1 += vy*s2;
  }
  rede[wv][lane*2] = e0; rede[wv][lane*2+1] = e1;
  redp[wv][lane*2] = p0; redp[wv][lane*2+1] = p1;
  __syncthreads();
  if (t < 128){
    fembb[(size_t)f*128 + t] = bfr(rede[0][t] + rede[1][t] + rede[2][t] + rede[3][t]);
    float pp = redp[0][t] + redp[1][t] + redp[2][t] + redp[3][t];
    atomAddF(&pooled[t], pp);
  }
}

// ---------------- attention-pool context (parallel colsum) ----------------
__global__ __launch_bounds__(1024) void attc2_k(const float* __restrict__ fsum, float Ninv,
                                                const float* __restrict__ Watt,
                                                float* __restrict__ attc)
{
  __shared__ float part[8][128];
  __shared__ float mean[128];
  int t = threadIdx.x;
  int j = t & 127, ch = t >> 7;
  float a = 0;
  for (int f = ch; f < FFUNC; f += 8) a += fsum[(size_t)f*128 + j];
  part[ch][j] = a;
  __syncthreads();
  if (t < 128){
    float m = 0;
    #pragma unroll
    for (int c=0;c<8;c++) m += part[c][t];
    mean[t] = m * Ninv;
  }
  __syncthreads();
  if (t < 128){
    float c = 0;
    for (int k=0;k<128;k++) c += mean[k]*Watt[(size_t)k*128 + t];
    attc[t] = tanhf(c);
  }
}

// ---------------- MFMA similarity GEMM (NT, bf16) + min/max ----------------
__global__ __launch_bounds__(256) void gemmnt_b(const unsigned short* __restrict__ fa,
                                                const unsigned short* __restrict__ fb,
                                                float* __restrict__ sc,
                                                unsigned* __restrict__ mmk)
{
  int t = threadIdx.x;
  int l = t & 63, w = t >> 6, b = l >> 4, m = l & 15;
  int rowbase = blockIdx.y*64 + w*16;
  int colbase = blockIdx.x*64;
  f4v acc[4];
  #pragma unroll
  for (int nt=0; nt<4; nt++) acc[nt] = (f4v){0,0,0,0};
  #pragma unroll
  for (int kt=0; kt<4; kt++){
    int arow = rowbase + m;
    s8v af = (s8v){0,0,0,0,0,0,0,0};
    if (arow < FFUNC) af = *(const s8v*)(fa + (size_t)arow*128 + kt*32 + b*8);
    #pragma unroll
    for (int nt=0; nt<4; nt++){
      int brow = colbase + nt*16 + m;
      s8v bf = (s8v){0,0,0,0,0,0,0,0};
      if (brow < FFUNC) bf = *(const s8v*)(fb + (size_t)brow*128 + kt*32 + b*8);
      acc[nt] = __builtin_amdgcn_mfma_f32_16x16x32_bf16(af, bf, acc[nt], 0, 0, 0);
    }
  }
  float mn = INFINITY, mx = -INFINITY;
  #pragma unroll
  for (int nt=0; nt<4; nt++){
    #pragma unroll
    for (int r2=0; r2<4; r2++){
      int row = rowbase + 4*b + r2;
      int col = colbase + nt*16 + m;
      if (row < FFUNC && col < FFUNC){
        float v = acc[nt][r2];
        sc[(size_t)row*FFUNC + col] = v;
        mn = fminf(mn, v); mx = fmaxf(mx, v);
      }
    }
  }
  __shared__ float smn[256], smx[256];
  smn[t]=mn; smx[t]=mx; __syncthreads();
  for (int o=128;o>0;o>>=1){
    if (t<o){ smn[t]=fminf(smn[t],smn[t+o]); smx[t]=fmaxf(smx[t],smx[t+o]); }
    __syncthreads();
  }
  if (t==0){ atomicMin(&mmk[0], fkey(smn[0])); atomicMax(&mmk[1], fkey(smx[0])); }
}

__global__ void hist_init_k(unsigned* mmk, unsigned* hist){
  int t = threadIdx.x;
  if (t==0){ mmk[0]=0xFFFFFFFFu; mmk[1]=0u; }
  if (t<16) hist[t]=0u;
}

__global__ void hist_k(const float* __restrict__ sc, const unsigned* __restrict__ mmk,
                       unsigned* __restrict__ hist)
{
  __shared__ unsigned hl[16];
  int t = threadIdx.x;
  if (t < 16) hl[t] = 0;
  __syncthreads();
  float mn = funkey(mmk[0]), mx = funkey(mmk[1]);
  float rng = fmaxf(mx - mn, 1e-12f);
  const long total = (long)FFUNC*FFUNC;
  for (long idx = (long)blockIdx.x*256 + t; idx < total; idx += (long)gridDim.x*256){
    float v = sc[idx];
    int b = (int)floorf((v - mn)/rng * 16.0f);
    b = min(max(b,0),15);
    atomicAdd(&hl[b], 1u);
  }
  __syncthreads();
  if (t < 16) atomicAdd(&hist[t], hl[t]);
}

// ---------------- final head ----------------
__global__ __launch_bounds__(256) void final_k(
    const float* __restrict__ p1, const float* __restrict__ p2,
    const float* __restrict__ Wtn, const float* __restrict__ Vtn,
    const float* __restrict__ btn, const unsigned* __restrict__ hist,
    const float* __restrict__ Wfc1, const float* __restrict__ bfc1,
    const float* __restrict__ Wsc, const float* __restrict__ bsc,
    float* __restrict__ outp)
{
  __shared__ float P1[128], P2[128], part[256], feats[32], hv[16];
  int t = threadIdx.x;
  if (t < 128){ P1[t] = p1[t]; P2[t] = p2[t]; }
  __syncthreads();
  int k = t & 15, pr_ = t >> 4;
  float acc = 0;
  for (int i = pr_*8; i < pr_*8+8; ++i){
    float pi = P1[i];
    const float* wrow = Wtn + ((size_t)i*128)*16 + k;
    float a2 = 0;
    for (int j=0;j<128;++j) a2 += P2[j]*wrow[(size_t)j*16];
    acc += pi*a2;
  }
  part[t] = acc;
  __syncthreads();
  if (t < 16){
    float sc_ = 0;
    for (int p=0;p<16;p++) sc_ += part[p*16 + t];
    float bl = btn[t];
    for (int j=0;j<256;j++) bl += Vtn[(size_t)t*256 + j] * (j<128 ? P1[j] : P2[j-128]);
    float tv = sc_ + bl;
    feats[t] = tv > 0.f ? tv : 0.f;
    feats[16+t] = (float)hist[t] * (1.0f/((float)FFUNC*(float)FFUNC));
  }
  __syncthreads();
  if (t < 16){
    float a2 = bfc1[t];
    for (int q2=0;q2<32;q2++) a2 += feats[q2]*Wfc1[q2*16 + t];
    hv[t] = a2 > 0.f ? a2 : 0.f;
  }
  __syncthreads();
  if (t == 0){
    float z = bsc[0];
    for (int m=0;m<16;m++) z += hv[m]*Wsc[m];
    outp[0] = sigf(z);
  }
}

// ---------------- host ----------------
extern "C" void kernel_launch(void* const* d_in, const int* in_sizes, int n_in,
                              void* d_out, int out_size, void* d_ws, size_t ws_size,
                              hipStream_t stream)
{
  (void)n_in; (void)out_size; (void)ws_size;
  const float* Wk = (const float*)d_in[16];
  const float* bk = (const float*)d_in[17];
  const float* Wq = (const float*)d_in[18];
  const float* bq = (const float*)d_in[19];
  const float* Wv = (const float*)d_in[20];
  const float* bv = (const float*)d_in[21];
  const float* Wa = (const float*)d_in[22];
  const float* ba = (const float*)d_in[23];
  const float* SKp = (const float*)d_in[24];
  const float* AR = (const float*)d_in[25];
  const float* MRm = (const float*)d_in[26];
  const float* PRp = (const float*)d_in[27];
  const float* WATT = (const float*)d_in[28];
  const float* WTN = (const float*)d_in[29];
  const float* VTN = (const float*)d_in[30];
  const float* BTN = (const float*)d_in[31];
  const float* WFC1 = (const float*)d_in[32];
  const float* BFC1 = (const float*)d_in[33];
  const float* WSC = (const float*)d_in[34];
  const float* BSC = (const float*)d_in[35];

  int NdA[2] = { in_sizes[0]/128, in_sizes[8]/128 };
  int NiA[2] = { in_sizes[1]/128, in_sizes[9]/128 };
  int EA[2][4];
  for (int g=0; g<2; g++)
    for (int r=0; r<4; r++) EA[g][r] = in_sizes[g*8+2+r]/2;

  int NdM = NdA[0] > NdA[1] ? NdA[0] : NdA[1];
  int NiM = NiA[0] > NiA[1] ? NiA[0] : NiA[1];
  long EtotM = 0;
  for (int g=0; g<2; g++){
    long et = 0; for (int r=0;r<4;r++) et += EA[g][r];
    if (et > EtotM) EtotM = et;
  }
  size_t nrowsM = (size_t)NdM + (size_t)NiM;
  int NOR = (int)(((nrowsM + 2 + 63)/64)*64);
  long KR4rows = 3L*NiM + NdM;

  char* wp = (char*)d_ws;
  auto alloc = [&](size_t bytes)->void*{
    void* p = (void*)wp;
    wp += (bytes + 255) & ~(size_t)255;
    return p;
  };
  unsigned short* Xb   = (unsigned short*)alloc(nrowsM*128*2);
  unsigned short* AGGb = (unsigned short*)alloc(nrowsM*128*2);
  float*          DEN  = (float*)alloc(nrowsM*4*4);
  unsigned short* O1b  = (unsigned short*)alloc(nrowsM*128*2);
  unsigned short* Qb   = (unsigned short*)alloc(nrowsM*128*2);
  unsigned short* KRK  = (unsigned short*)alloc((size_t)KR4rows*128*2);
  unsigned short* KRV  = (unsigned short*)alloc((size_t)KR4rows*128*2);
  int*            OFFS3= (int*)alloc((size_t)3*NOR*4);   // dir0, dir1, func
  int*            PERM = (int*)alloc((size_t)2*EtotM*4);
  int*            FPERM= (int*)alloc(nrowsM*4);
  int*            PART = (int*)alloc((size_t)3*1024*4);
  float*          GS[2];
  GS[0] = (float*)alloc((size_t)257280*4);
  GS[1] = (float*)alloc((size_t)257280*4);
  unsigned short* FB[2];
  FB[0] = (unsigned short*)alloc((size_t)FFUNC*128*2);
  FB[1] = (unsigned short*)alloc((size_t)FFUNC*128*2);
  unsigned*       MM   = (unsigned*)alloc(2*4);
  unsigned*       HIST = (unsigned*)alloc(16*4);
  unsigned short* WKP  = (unsigned short*)alloc((size_t)8*16384*2);
  unsigned short* WQP  = (unsigned short*)alloc((size_t)8*16384*2);
  unsigned short* WVP  = (unsigned short*)alloc((size_t)8*16384*2);
  unsigned short* WAP  = (unsigned short*)alloc((size_t)8*16384*2);
  unsigned short* WATTP= (unsigned short*)alloc((size_t)16384*2);
  unsigned short* ARP  = (unsigned short*)alloc((size_t)16*4096*2);
  unsigned short* MRP  = (unsigned short*)alloc((size_t)16*4096*2);
  size_t uni_bytes = (size_t)FFUNC*FFUNC*4;
  size_t curs_bytes = (size_t)3*NOR*4;
  void* UNI = alloc(uni_bytes > curs_bytes ? uni_bytes : curs_bytes);
  int*   CURS3 = (int*)UNI;
  float* SCb   = (float*)UNI;

  packw_k<<<8,256,0,stream>>>(Wk, WKP);
  packw_k<<<8,256,0,stream>>>(Wq, WQP);
  packw_k<<<8,256,0,stream>>>(Wv, WVP);
  packw_k<<<8,256,0,stream>>>(Wa, WAP);
  packw_k<<<1,256,0,stream>>>(WATT, WATTP);
  packa_k<<<16,256,0,stream>>>(AR, ARP);
  packa_k<<<16,256,0,stream>>>(MRm, MRP);

  const size_t OF_FSUM=0, OF_FCNT=128000, OF_CF=129024, OF_ATTC=257024, OF_POOL=257152;
  const int stf[4] = {1,0,1,1};
  const int dtf[4] = {1,1,0,1};

  for (int g=0; g<2; ++g){
    int nd = NdA[g], ni = NiA[g];
    int nrows = nd + ni;
    int E[4] = {EA[g][0],EA[g][1],EA[g][2],EA[g][3]};
    const int* ei[4] = {(const int*)d_in[g*8+2], (const int*)d_in[g*8+3],
                        (const int*)d_in[g*8+4], (const int*)d_in[g*8+5]};
    const int* fdp = (const int*)d_in[g*8+6];
    const int* fip = (const int*)d_in[g*8+7];
    const float* x0d = (const float*)d_in[g*8+0];
    const float* x0i = (const float*)d_in[g*8+1];
    int gbd = (nd+63)/64, gbi = (ni+63)/64;
    int nb = gbd + gbi;
    int ntb = (nrows+255)/256; if (ntb > 2048) ntb = 2048;

    int koff[2][4], stA[2][4], dtA[2][4];
    for (int c=0;c<2;c++){
      int run = 0;
      for (int r=0;r<4;r++){
        stA[c][r] = (c==0) ? stf[r] : dtf[r];
        dtA[c][r] = (c==0) ? dtf[r] : stf[r];
        koff[c][r] = run;
        run += stA[c][r] ? ni : nd;
      }
    }

    // ---- build 2 merged edge CSRs + function CSR ----
    hipMemsetAsync(OFFS3, 0, (size_t)3*NOR*4, stream);
    HD hd; int hb = 0;
    for (int c2=0; c2<2; c2++)
      for (int r=0; r<4; r++){
        int ent = c2*4 + r;
        hd.blk0[ent] = hb;
        hd.dst[ent] = (c2==0) ? ei[r]+E[r] : ei[r];
        hd.src[ent] = (c2==0) ? ei[r] : ei[r]+E[r];
        hd.E[ent] = E[r];
        hd.cnto[ent] = c2*NOR + (dtA[c2][r] ? nd : 0);
        hd.permo[ent] = c2*(int)EtotM;
        hb += (E[r]+255)/256;
      }
    hd.blk0[8] = hb;
    csr_hist_all_k<<<hb,256,0,stream>>>(hd, OFFS3);
    fhist_k<<<ntb,256,0,stream>>>(fdp, fip, nd, ni, OFFS3 + (size_t)2*NOR);
    ScanDesc sd; sd.n[0] = nrows; sd.n[1] = nrows; sd.n[2] = FFUNC;
    int maxtiles = (nrows + 1023)/1024; if (maxtiles < 1) maxtiles = 1;
    dim3 sgrid(maxtiles, 3);
    scan_p1<<<sgrid,1024,0,stream>>>(sd, OFFS3, PART, NOR, maxtiles);
    scan_p2<<<1,1024,0,stream>>>(PART, maxtiles, 3);
    scan_p3<<<sgrid,1024,0,stream>>>(sd, OFFS3, CURS3, PART, NOR, maxtiles);
    csr_fill_all_k<<<hb,256,0,stream>>>(hd, CURS3, PERM);
    ffill_k<<<ntb,256,0,stream>>>(fdp, fip, nd, ni, CURS3 + (size_t)2*NOR, FPERM);

    for (int l=0; l<2; ++l){
      const void* xd = (l==0) ? (const void*)x0d : (const void*)Xb;
      const void* xi = (l==0) ? (const void*)x0i : (const void*)(Xb + (size_t)nd*128);
      int af32 = (l==0);
      for (int c=0; c<2; ++c){
        int pc = l*2 + c;
        KX kx;
        for (int r=0;r<4;r++){ kx.styp[r] = stA[c][r]; kx.koff[r] = koff[c][r]; }
        gemm_kqvx_k<<<nb,256,0,stream>>>(
            xd, xi, af32, nd, ni, gbd,
            WKP+(size_t)pc*2*16384, WQP+(size_t)pc*2*16384, WVP+(size_t)pc*2*16384,
            bk+(size_t)pc*2*128, bq+(size_t)pc*2*128, bv+(size_t)pc*2*128,
            ARP + (size_t)pc*4*4096, MRP + (size_t)pc*4*4096,
            Qb, KRK, KRV, kx);
        MD md;
        for (int r=0;r<4;r++) md.koff[r] = koff[c][r];
        int eblk = (nrows*32 + 255)/256;
        e12m_k<<<eblk,256,0,stream>>>(KRK, KRV, Qb,
                                      OFFS3 + (size_t)c*NOR, PERM + (size_t)c*EtotM, nrows,
                                      PRp + (size_t)pc*16, AGGb, DEN, md);
        gemm_epi_k<<<nb,256,0,stream>>>(
            AGGb, DEN, nd, ni, gbd,
            WAP+(size_t)pc*2*16384, ba+(size_t)pc*2*128,
            xd, xi, af32,
            (c==1) ? O1b : (const unsigned short*)nullptr,
            (c==0) ? O1b : Xb,
            SKp + (size_t)pc*2, (c==0) ? 2 : 3);
      }
    }
    // pooling (function-CSR, bf16 X)
    float* fsum = GS[g]+OF_FSUM;  float* fcnt = GS[g]+OF_FCNT;
    float* cf   = GS[g]+OF_CF;    float* attc = GS[g]+OF_ATTC;
    float* pool = GS[g]+OF_POOL;
    hipMemsetAsync(pool, 0, 128*4, stream);
    f1c_k<<<FFUNC,256,0,stream>>>(Xb, OFFS3 + (size_t)2*NOR, FPERM, fsum, fcnt);
    attc2_k<<<1,1024,0,stream>>>(fsum, 1.0f/(float)nrows, WATT, attc);
    gemmb_k<<<(FFUNC+63)/64,256,0,stream>>>(fsum, FFUNC, WATTP, nullptr, cf, 1, fcnt);
    f23c_k<<<FFUNC,256,0,stream>>>(Xb, OFFS3 + (size_t)2*NOR, FPERM, cf, attc, FB[g], pool);
  }
  // similarity histogram + final head
  hist_init_k<<<1,32,0,stream>>>(MM, HIST);
  dim3 gnt((FFUNC+63)/64, (FFUNC+63)/64);
  gemmnt_b<<<gnt,256,0,stream>>>(FB[0], FB[1], SCb, MM);
  hist_k<<<512,256,0,stream>>>(SCb, MM, HIST);
  final_k<<<1,256,0,stream>>>(GS[0]+OF_POOL, GS[1]+OF_POOL, WTN, VTN, BTN, HIST,
                              WFC1, BFC1, WSC, BSC, (float*)d_out);
}

// Round 15
// 1605.989 us; speedup vs baseline: 1.2174x; 1.1178x over previous
//
#include <hip/hip_runtime.h>
#include <math.h>

#define FFUNC 1000

typedef __attribute__((ext_vector_type(8))) short s8v;
typedef __attribute__((ext_vector_type(4))) float f4v;

// ---------------- device helpers ----------------
__device__ __forceinline__ float sigf(float x){ return 1.0f/(1.0f+__expf(-x)); }
__device__ __forceinline__ float geluf(float x){
  float u = 1.5957691216057308f * (x + 0.044715f*x*x*x);
  return x / (1.0f + __expf(-u));
}
__device__ __forceinline__ unsigned fkey(float f){
  unsigned u = __float_as_uint(f);
  return (u & 0x80000000u) ? ~u : (u | 0x80000000u);
}
__device__ __forceinline__ float funkey(unsigned k){
  unsigned u = (k & 0x80000000u) ? (k ^ 0x80000000u) : ~k;
  return __uint_as_float(u);
}
__device__ __forceinline__ void atomAddF(float* p, float v){ unsafeAtomicAdd(p, v); }
__device__ __forceinline__ unsigned short bfr(float x){   // f32 -> bf16 RNE
  unsigned u = __float_as_uint(x);
  unsigned r = (u + 0x7FFFu + ((u >> 16) & 1u)) >> 16;
  return (unsigned short)r;
}
__device__ __forceinline__ float b2f(unsigned short v){
  return __uint_as_float((unsigned)v << 16);
}

// ---------------- weight prepack (Wq, Wa, Watt only) ----------------
__global__ void packw_k(const float* __restrict__ W, unsigned short* __restrict__ out){
  int mat = blockIdx.x;
  const float* w = W + (size_t)mat*16384;
  unsigned short* o = out + (size_t)mat*16384;
  for (int u=0; u<64; u++){
    int oi = u*256 + threadIdx.x;
    int j = oi & 7, l = (oi>>3) & 63, nt = (oi>>9) & 7, kt = oi >> 12;
    float v = w[(size_t)(kt*32 + 8*(l>>4) + j)*128 + nt*16 + (l&15)];
    o[oi] = bfr(v);
  }
}

// ---------------- composite weight precompute ----------------
// b = kv*32 + (pc*2+c)*4 + r ; composite = W[pc][styp] @ blockdiag(a[pc][r]) (f32 -> packed bf16)
// bias composite = b[pc][styp] @ blockdiag(a)
__global__ __launch_bounds__(256) void comp_k(
    const float* __restrict__ Wk, const float* __restrict__ bk,
    const float* __restrict__ Wv, const float* __restrict__ bv,
    const float* __restrict__ AR, const float* __restrict__ MR,
    unsigned short* __restrict__ OC, float* __restrict__ OB)
{
  const int stf[4]={1,0,1,1}, dtf[4]={1,1,0,1};
  int b = blockIdx.x, kv = b>>5, idx = b&31, pcc = idx>>2, r = idx&3;
  int pc = pcc>>1, c = pcc&1;
  int styp = (c==0) ? stf[r] : dtf[r];
  const float* W  = (kv ? Wv : Wk) + (size_t)(pc*2+styp)*16384;
  const float* bi = (kv ? bv : bk) + (size_t)(pc*2+styp)*128;
  const float* a  = (kv ? MR : AR) + (size_t)(pc*4+r)*4096;
  unsigned short* oc = OC + (size_t)b*16384;
  float* ob = OB + (size_t)b*128;
  __shared__ float as[4096];
  for (int i=threadIdx.x; i<4096; i+=256) as[i] = a[i];
  __syncthreads();
  for (int u=0; u<64; u++){
    int oi = u*256 + threadIdx.x;
    int j = oi&7, l = (oi>>3)&63, nt = (oi>>9)&7, kt = oi>>12;
    int k = kt*32 + 8*(l>>4) + j;
    int col = nt*16 + (l&15);
    int h = col>>5, f = col&31;
    const float* wr = W + (size_t)k*128 + h*32;
    const float* ap = as + h*1024 + f;
    float s = 0;
    #pragma unroll 8
    for (int d=0; d<32; d++) s += wr[d]*ap[d*32];
    oc[oi] = bfr(s);
  }
  if (threadIdx.x < 128){
    int col = threadIdx.x, h = col>>5, f = col&31;
    float s = 0;
    for (int d=0; d<32; d++) s += bi[h*32+d]*as[h*1024 + d*32 + f];
    ob[col] = s;
  }
}

// ---------------- multi-output projection GEMM (composite weights) ----------------
struct OutD { const unsigned short* w; const float* bi; unsigned short* dst; };
struct KSet { int nout; OutD o[7]; };
__global__ __launch_bounds__(256) void gemm_kqvc_k(
    const void* __restrict__ xdv, const void* __restrict__ xiv, int af32,
    int nd, int ni, int gbd, KSet kd, KSet ki)
{
  __shared__ __align__(16) unsigned short tile[2][64*128];
  int blk = blockIdx.x;
  int ty = (blk >= gbd);
  int N = ty ? ni : nd;
  int rbase = (ty ? (blk - gbd) : blk) * 64;
  const float* Af = (const float*)(ty ? xiv : xdv);
  const unsigned short* Ab = (const unsigned short*)(ty ? xiv : xdv);

  int t = threadIdx.x;
  int l = t & 63, w = t >> 6, b = l >> 4, m = l & 15;
  int arow = rbase + w*16 + m;
  bool rv = arow < N;

  // input A-fragments, held across all outputs
  s8v axf[4];
  #pragma unroll
  for (int kt=0; kt<4; kt++){
    s8v af = (s8v){0,0,0,0,0,0,0,0};
    if (rv){
      if (af32){
        const float* ap = Af + (size_t)arow*128 + kt*32 + b*8;
        float4 x0 = *(const float4*)ap;
        float4 x1 = *(const float4*)(ap + 4);
        af[0]=(short)bfr(x0.x); af[1]=(short)bfr(x0.y); af[2]=(short)bfr(x0.z); af[3]=(short)bfr(x0.w);
        af[4]=(short)bfr(x1.x); af[5]=(short)bfr(x1.y); af[6]=(short)bfr(x1.z); af[7]=(short)bfr(x1.w);
      } else {
        af = *(const s8v*)(Ab + (size_t)arow*128 + kt*32 + b*8);
      }
    }
    axf[kt] = af;
  }

  int nout = ty ? ki.nout : kd.nout;
  int cur = 0;
  for (int i=0; i<nout; i++){
    const unsigned short* wp = ty ? ki.o[i].w   : kd.o[i].w;
    const float*          bi = ty ? ki.o[i].bi  : kd.o[i].bi;
    unsigned short*      dst = ty ? ki.o[i].dst : kd.o[i].dst;
    f4v acc[8];
    #pragma unroll
    for (int nt=0; nt<8; nt++) acc[nt] = (f4v){0,0,0,0};
    #pragma unroll
    for (int kt=0; kt<4; kt++)
      #pragma unroll
      for (int nt=0; nt<8; nt++){
        s8v bf = *(const s8v*)(wp + ((kt*8 + nt)*64 + l)*8);
        acc[nt] = __builtin_amdgcn_mfma_f32_16x16x32_bf16(axf[kt], bf, acc[nt], 0, 0, 0);
      }
    // stage (bias added) into swizzled tile[cur]
    #pragma unroll
    for (int r2=0; r2<4; r2++){
      int trow = w*16 + 4*b + r2;
      #pragma unroll
      for (int nt=0; nt<8; nt++){
        int col = nt*16 + m;
        int ch = (col>>3) ^ (trow&15);
        tile[cur][trow*128 + ch*8 + (col&7)] = bfr(acc[nt][r2] + bi[col]);
      }
    }
    __syncthreads();
    // wide store
    #pragma unroll
    for (int it=0; it<4; it++){
      int idx = it*256 + t;
      int rr = idx >> 4, cc = idx & 15;
      int orow = rbase + rr;
      if (orow < N)
        *(uint4*)(dst + (size_t)orow*128 + cc*8) =
            *(const uint4*)(&tile[cur][rr*128 + ((cc ^ (rr&15))*8)]);
    }
    cur ^= 1;
  }
}

// ---------------- fused epilogue GEMM (LDS-staged wide epilogue) ----------------
__global__ __launch_bounds__(256) void gemm_epi_k(
    const unsigned short* __restrict__ AGGb, const float* __restrict__ DENb,
    int nd, int ni, int gbd,
    const unsigned short* __restrict__ WA, const float* __restrict__ bA,
    const void* __restrict__ xin_dv, const void* __restrict__ xin_iv, int xf32,
    const unsigned short* __restrict__ o1p, unsigned short* __restrict__ out,
    const float* __restrict__ skp, int mode)
{
  __shared__ __align__(16) float ftile[64*128];
  int blk = blockIdx.x;
  int ty = (blk >= gbd);
  int N = ty ? ni : nd;
  int rbase = (ty ? (blk - gbd) : blk) * 64;
  int goff = ty ? nd : 0;
  const unsigned short* wa = WA + (ty ? 16384 : 0);
  const float* ba2 = bA + (ty ? 128 : 0);
  const float* xinF = (const float*)(ty ? xin_iv : xin_dv);
  const unsigned short* xinB = (const unsigned short*)(ty ? xin_iv : xin_dv);
  float s = sigf(skp[ty]), s1 = 1.0f - s;

  int t = threadIdx.x;
  int l = t & 63, w = t >> 6, b = l >> 4, m = l & 15;
  int arow = rbase + w*16 + m;
  bool rv = arow < N;
  f4v acc[8];
  #pragma unroll
  for (int nt=0; nt<8; nt++) acc[nt] = (f4v){0,0,0,0};

  float4 dv4 = make_float4(1.f,1.f,1.f,1.f);
  if (rv){
    size_t grow = (size_t)(goff + arow);
    float4 dr = *(const float4*)(DENb + grow*4);
    dv4.x = 1.0f / fmaxf(dr.x, 1e-16f);
    dv4.y = 1.0f / fmaxf(dr.y, 1e-16f);
    dv4.z = 1.0f / fmaxf(dr.z, 1e-16f);
    dv4.w = 1.0f / fmaxf(dr.w, 1e-16f);
  }
  #pragma unroll
  for (int kt=0; kt<4; kt++){
    s8v af = (s8v){0,0,0,0,0,0,0,0};
    if (rv){
      size_t grow = (size_t)(goff + arow);
      float dv = (kt==0)?dv4.x:(kt==1)?dv4.y:(kt==2)?dv4.z:dv4.w;
      s8v ag = *(const s8v*)(AGGb + grow*128 + kt*32 + b*8);
      #pragma unroll
      for (int jj=0; jj<8; jj++)
        af[jj] = (short)bfr(geluf(b2f((unsigned short)ag[jj]) * dv));
    }
    #pragma unroll
    for (int nt=0; nt<8; nt++){
      s8v bf = *(const s8v*)(wa + ((kt*8 + nt)*64 + l)*8);
      acc[nt] = __builtin_amdgcn_mfma_f32_16x16x32_bf16(af, bf, acc[nt], 0, 0, 0);
    }
  }
  // stage f32 acc into swizzled tile
  #pragma unroll
  for (int r2=0; r2<4; r2++){
    int trow = w*16 + 4*b + r2;
    #pragma unroll
    for (int nt=0; nt<8; nt++){
      int col = nt*16 + m;
      int ch = (col>>2) ^ (trow&31);
      ftile[trow*128 + ch*4 + (col&3)] = acc[nt][r2];
    }
  }
  __syncthreads();
  // wide epilogue: bias + skip (+combine) + store
  #pragma unroll
  for (int it=0; it<8; it++){
    int idx = it*256 + t;          // row*32 + chunk
    int rr = idx >> 5, cc = idx & 31;
    int orow = rbase + rr;
    if (orow >= N) continue;
    size_t grow = (size_t)(goff + orow);
    float4 a4 = *(const float4*)(&ftile[rr*128 + ((cc ^ (rr&31))*4)]);
    float4 b4 = *(const float4*)(ba2 + cc*4);
    float xv0, xv1, xv2, xv3;
    if (xf32){
      float4 x4 = *(const float4*)(xinF + (size_t)orow*128 + cc*4);
      xv0=x4.x; xv1=x4.y; xv2=x4.z; xv3=x4.w;
    } else {
      ushort4 x4 = *(const ushort4*)(xinB + (size_t)orow*128 + cc*4);
      xv0=b2f(x4.x); xv1=b2f(x4.y); xv2=b2f(x4.z); xv3=b2f(x4.w);
    }
    float v0 = s*(a4.x + b4.x) + s1*xv0;
    float v1 = s*(a4.y + b4.y) + s1*xv1;
    float v2 = s*(a4.z + b4.z) + s1*xv2;
    float v3 = s*(a4.w + b4.w) + s1*xv3;
    if (mode == 3){
      ushort4 o4 = *(const ushort4*)(o1p + grow*128 + cc*4);
      v0 = fmaxf(0.5f*b2f(o4.x) + 0.5f*v0, 0.f);
      v1 = fmaxf(0.5f*b2f(o4.y) + 0.5f*v1, 0.f);
      v2 = fmaxf(0.5f*b2f(o4.z) + 0.5f*v2, 0.f);
      v3 = fmaxf(0.5f*b2f(o4.w) + 0.5f*v3, 0.f);
    }
    *(ushort4*)(out + grow*128 + cc*4) =
        make_ushort4(bfr(v0), bfr(v1), bfr(v2), bfr(v3));
  }
}

// ---------------- merged CSR build ----------------
struct ScanDesc { int n[8]; };

struct HD {
  int blk0[9];
  const int* dst[8];
  const int* src[8];
  int E[8];
  int cnto[8];
  int permo[8];
};
__global__ void csr_hist_all_k(HD d, int* __restrict__ cnt){
  int b = blockIdx.x;
  int r = 0;
  while (r < 7 && b >= d.blk0[r+1]) r++;
  int e = (b - d.blk0[r])*256 + threadIdx.x;
  if (e < d.E[r]) atomicAdd(&cnt[d.cnto[r] + d.dst[r][e]], 1);
}
__global__ void csr_fill_all_k(HD d, int* __restrict__ curs, int* __restrict__ perm){
  int b = blockIdx.x;
  int r = 0;
  while (r < 7 && b >= d.blk0[r+1]) r++;
  int e = (b - d.blk0[r])*256 + threadIdx.x;
  if (e < d.E[r]){
    int pos = atomicAdd(&curs[d.cnto[r] + d.dst[r][e]], 1);
    perm[d.permo[r] + pos] = d.src[r][e] | ((r & 3) << 24);
  }
}

// ---------------- parallel 3-phase scan ----------------
__global__ __launch_bounds__(1024) void scan_p1(ScanDesc sd, const int* __restrict__ offs,
                                                int* __restrict__ part, int NO, int MAXT){
  int ent = blockIdx.y, tile = blockIdx.x;
  int n = sd.n[ent];
  int i = tile*1024 + threadIdx.x;
  int v = (i < n) ? offs[(size_t)ent*NO + i] : 0;
  #pragma unroll
  for (int d2=1; d2<64; d2<<=1) v += __shfl_xor(v, d2, 64);
  __shared__ int ws_[16];
  int lane = threadIdx.x & 63, wv = threadIdx.x >> 6;
  if (lane == 0) ws_[wv] = v;
  __syncthreads();
  if (threadIdx.x == 0){
    int s = 0;
    #pragma unroll
    for (int k=0;k<16;k++) s += ws_[k];
    part[ent*MAXT + tile] = s;
  }
}

__global__ __launch_bounds__(1024) void scan_p2(int* __restrict__ part, int MAXT, int nent){
  int tid = threadIdx.x, lane = tid & 63, wv = tid >> 6;
  __shared__ int wsum[16];
  __shared__ int woff[17];
  for (int ent=0; ent<nent; ent++){
    int v = (tid < MAXT) ? part[ent*MAXT + tid] : 0;
    int s = v;
    #pragma unroll
    for (int d2=1; d2<64; d2<<=1){
      int t2 = __shfl_up(s, d2, 64);
      if (lane >= d2) s += t2;
    }
    if (lane == 63) wsum[wv] = s;
    __syncthreads();
    if (wv == 0 && lane < 16){
      int x = wsum[lane];
      #pragma unroll
      for (int d2=1; d2<16; d2<<=1){
        int t2 = __shfl_up(x, d2, 64);
        if (lane >= d2) x += t2;
      }
      woff[lane+1] = x;
      if (lane == 0) woff[0] = 0;
    }
    __syncthreads();
    if (tid < MAXT) part[ent*MAXT + tid] = woff[wv] + s - v;
    __syncthreads();
  }
}

__global__ __launch_bounds__(1024) void scan_p3(ScanDesc sd, int* __restrict__ offs,
                                                int* __restrict__ curs,
                                                const int* __restrict__ part, int NO, int MAXT){
  int ent = blockIdx.y, tile = blockIdx.x;
  int n = sd.n[ent];
  int i = tile*1024 + threadIdx.x;
  int v = (i < n) ? offs[(size_t)ent*NO + i] : 0;
  int lane = threadIdx.x & 63, wv = threadIdx.x >> 6;
  int s = v;
  #pragma unroll
  for (int d2=1; d2<64; d2<<=1){
    int t2 = __shfl_up(s, d2, 64);
    if (lane >= d2) s += t2;
  }
  __shared__ int wsum[16];
  __shared__ int woff[17];
  if (lane == 63) wsum[wv] = s;
  __syncthreads();
  if (wv == 0 && lane < 16){
    int x = wsum[lane];
    #pragma unroll
    for (int d2=1; d2<16; d2<<=1){
      int t2 = __shfl_up(x, d2, 64);
      if (lane >= d2) x += t2;
    }
    woff[lane+1] = x;
    if (lane == 0) woff[0] = 0;
  }
  __syncthreads();
  int excl = part[ent*MAXT + tile] + woff[wv] + s - v;
  if (i < n){
    offs[(size_t)ent*NO + i] = excl;
    curs[(size_t)ent*NO + i] = excl;
  }
  if (i == n-1) offs[(size_t)ent*NO + n] = excl + v;
}

// ---------------- function-CSR build ----------------
__global__ void fhist_k(const int* __restrict__ fd, const int* __restrict__ fi,
                        int Nd, int Ni, int* __restrict__ cnt){
  int nt = Nd + Ni;
  for (int n = blockIdx.x*256 + threadIdx.x; n < nt; n += gridDim.x*256){
    int f = (n < Nd) ? fd[n] : fi[n-Nd];
    atomicAdd(&cnt[f], 1);
  }
}
__global__ void ffill_k(const int* __restrict__ fd, const int* __restrict__ fi,
                        int Nd, int Ni, int* __restrict__ curs, int* __restrict__ perm){
  int nt = Nd + Ni;
  for (int n = blockIdx.x*256 + threadIdx.x; n < nt; n += gridDim.x*256){
    int f = (n < Nd) ? fd[n] : fi[n-Nd];
    int pos = atomicAdd(&curs[f], 1);
    perm[pos] = n;
  }
}

// ---------------- E12 merged: online-softmax edge aggregation ----------------
struct MD { int koff[4]; };
__global__ __launch_bounds__(256) void e12m_k(
    const unsigned short* __restrict__ KRK, const unsigned short* __restrict__ KRV,
    const unsigned short* __restrict__ Qb,
    const int* __restrict__ offs, const int* __restrict__ perm, int nrows,
    const float* __restrict__ pr,
    unsigned short* __restrict__ aggb, float* __restrict__ den, MD md)
{
  int gidx = blockIdx.x*256 + threadIdx.x;
  int node = gidx >> 5; if (node >= nrows) return;
  int sub = gidx & 31, h = sub >> 3, j = sub & 7;
  int o0 = offs[node], o1 = offs[node+1];
  unsigned short* ap = aggb + (size_t)node*128 + h*32 + j*4;
  if (o0 == o1){
    *(ushort4*)ap = make_ushort4(0,0,0,0);
    if (j == 0) den[(size_t)node*4 + h] = 0.f;
    return;
  }
  ushort4 qa = *(const ushort4*)(Qb + (size_t)node*128 + h*32 + j*4);
  float q0=b2f(qa.x), q1=b2f(qa.y), q2=b2f(qa.z), q3=b2f(qa.w);
  float scl[4];
  #pragma unroll
  for (int r=0;r<4;r++) scl[r] = pr[r*4 + h] * 0.17677669529663687f;  // 1/sqrt(32)
  float mx = -INFINITY, ds = 0.f;
  float4 acc = make_float4(0.f,0.f,0.f,0.f);
  for (int i=o0; i<o1; ++i){
    int pk = perm[i];
    int src = pk & 0xFFFFFF, rel = pk >> 24;
    size_t rowo = (size_t)(md.koff[rel] + src)*128 + h*32 + j*4;
    ushort4 aa = *(const ushort4*)(KRK + rowo);
    ushort4 vv = *(const ushort4*)(KRV + rowo);
    float p = b2f(aa.x)*q0 + b2f(aa.y)*q1 + b2f(aa.z)*q2 + b2f(aa.w)*q3;
    p += __shfl_xor(p, 1, 8);
    p += __shfl_xor(p, 2, 8);
    p += __shfl_xor(p, 4, 8);
    float lg = p * scl[rel];
    float nm = fmaxf(mx, lg);
    float corr = __expf(mx - nm);
    float ev = __expf(lg - nm);
    acc.x = acc.x*corr + ev*b2f(vv.x);
    acc.y = acc.y*corr + ev*b2f(vv.y);
    acc.z = acc.z*corr + ev*b2f(vv.z);
    acc.w = acc.w*corr + ev*b2f(vv.w);
    ds = ds*corr + ev;
    mx = nm;
  }
  *(ushort4*)ap = make_ushort4(bfr(acc.x), bfr(acc.y), bfr(acc.z), bfr(acc.w));
  if (j == 0) den[(size_t)node*4 + h] = ds;
}

// ---------------- plain MFMA GEMM (cf only; optional per-row divide) ----------------
__global__ __launch_bounds__(256) void gemmb_k(
    const float* __restrict__ A, int N,
    const unsigned short* __restrict__ Wp, const float* __restrict__ bias,
    float* __restrict__ outf, int mode, const float* __restrict__ rdiv)
{
  int t = threadIdx.x;
  int l = t & 63, w = t >> 6, b = l >> 4, m = l & 15;
  int arow = blockIdx.x*64 + w*16 + m;
  bool rv = arow < N;
  float dv = 1.0f;
  if (rv && rdiv) dv = 1.0f / fmaxf(rdiv[arow], 1.0f);
  f4v acc[8];
  #pragma unroll
  for (int nt=0; nt<8; nt++) acc[nt] = (f4v){0,0,0,0};
  #pragma unroll
  for (int kt=0; kt<4; kt++){
    s8v af = (s8v){0,0,0,0,0,0,0,0};
    if (rv){
      const float* ap = A + (size_t)arow*128 + kt*32 + b*8;
      float4 x0 = *(const float4*)ap;
      float4 x1 = *(const float4*)(ap + 4);
      af[0]=(short)bfr(x0.x*dv); af[1]=(short)bfr(x0.y*dv); af[2]=(short)bfr(x0.z*dv); af[3]=(short)bfr(x0.w*dv);
      af[4]=(short)bfr(x1.x*dv); af[5]=(short)bfr(x1.y*dv); af[6]=(short)bfr(x1.z*dv); af[7]=(short)bfr(x1.w*dv);
    }
    #pragma unroll
    for (int nt=0; nt<8; nt++){
      s8v bf = *(const s8v*)(Wp + ((kt*8 + nt)*64 + l)*8);
      acc[nt] = __builtin_amdgcn_mfma_f32_16x16x32_bf16(af, bf, acc[nt], 0, 0, 0);
    }
  }
  #pragma unroll
  for (int r2=0; r2<4; r2++){
    int orow = blockIdx.x*64 + w*16 + 4*b + r2;
    if (orow >= N) continue;
    #pragma unroll
    for (int nt=0; nt<8; nt++){
      int col = nt*16 + m;
      float v = acc[nt][r2];
      if (bias) v += bias[col];
      if (mode == 1) v = tanhf(v);
      outf[(size_t)orow*128 + col] = v;
    }
  }
}

// ---------------- func pool (CSR, bf16 X): sums + counts ----------------
__global__ __launch_bounds__(256) void f1c_k(const unsigned short* __restrict__ X,
    const int* __restrict__ foffs, const int* __restrict__ fperm,
    float* __restrict__ fsum, float* __restrict__ fcnt)
{
  __shared__ __align__(16) float red[4][128];
  int t = threadIdx.x, wv = t >> 6, lane = t & 63;
  int f = blockIdx.x;
  int o0 = foffs[f], o1 = foffs[f+1];
  float a0 = 0, a1 = 0;
  for (int i = o0 + wv; i < o1; i += 4){
    ushort2 x = *(const ushort2*)(X + (size_t)fperm[i]*128 + lane*2);
    a0 += b2f(x.x); a1 += b2f(x.y);
  }
  red[wv][lane*2] = a0; red[wv][lane*2+1] = a1;
  __syncthreads();
  if (t < 128)
    fsum[(size_t)f*128 + t] = red[0][t] + red[1][t] + red[2][t] + red[3][t];
  if (t == 0) fcnt[f] = (float)(o1 - o0);
}

// ---------------- func pool (CSR, bf16 X): femb(bf16) + global attention pool ----------------
__global__ __launch_bounds__(256) void f23c_k(const unsigned short* __restrict__ X,
    const int* __restrict__ foffs, const int* __restrict__ fperm,
    const float* __restrict__ cf, const float* __restrict__ attc,
    unsigned short* __restrict__ fembb, float* __restrict__ pooled)
{
  __shared__ __align__(16) float rede[4][128];
  __shared__ __align__(16) float redp[4][128];
  int t = threadIdx.x, wv = t >> 6, lane = t & 63;
  int f = blockIdx.x;
  int o0 = foffs[f], o1 = foffs[f+1];
  float c0 = cf[(size_t)f*128 + lane*2], c1 = cf[(size_t)f*128 + lane*2 + 1];
  float t0 = attc[lane*2], t1 = attc[lane*2 + 1];
  float e0=0, e1=0, p0=0, p1=0;
  for (int i = o0 + wv; i < o1; i += 4){
    ushort2 xr = *(const ushort2*)(X + (size_t)fperm[i]*128 + lane*2);
    float vx = b2f(xr.x), vy = b2f(xr.y);
    union { double d; float2 f2; } u;
    u.f2.x = vx*c0 + vy*c1;
    u.f2.y = vx*t0 + vy*t1;
    #pragma unroll
    for (int m2=1; m2<64; m2<<=1){
      union { double d; float2 f2; } v;
      v.d = __shfl_xor(u.d, m2, 64);
      u.f2.x += v.f2.x; u.f2.y += v.f2.y;
    }
    float s1 = sigf(u.f2.x), s2 = sigf(u.f2.y);
    e0 += vx*s1; e1 += vy*s1;
    p0 += vx*s2; p1 += vy*s2;
  }
  rede[wv][lane*2] = e0; rede[wv][lane*2+1] = e1;
  redp[wv][lane*2] = p0; redp[wv][lane*2+1] = p1;
  __syncthreads();
  if (t < 128){
    fembb[(size_t)f*128 + t] = bfr(rede[0][t] + rede[1][t] + rede[2][t] + rede[3][t]);
    float pp = redp[0][t] + redp[1][t] + redp[2][t] + redp[3][t];
    atomAddF(&pooled[t], pp);
  }
}

// ---------------- attention-pool context (parallel colsum) ----------------
__global__ __launch_bounds__(1024) void attc2_k(const float* __restrict__ fsum, float Ninv,
                                                const float* __restrict__ Watt,
                                                float* __restrict__ attc)
{
  __shared__ float part[8][128];
  __shared__ float mean[128];
  int t = threadIdx.x;
  int j = t & 127, ch = t >> 7;
  float a = 0;
  for (int f = ch; f < FFUNC; f += 8) a += fsum[(size_t)f*128 + j];
  part[ch][j] = a;
  __syncthreads();
  if (t < 128){
    float m = 0;
    #pragma unroll
    for (int c=0;c<8;c++) m += part[c][t];
    mean[t] = m * Ninv;
  }
  __syncthreads();
  if (t < 128){
    float c = 0;
    for (int k=0;k<128;k++) c += mean[k]*Watt[(size_t)k*128 + t];
    attc[t] = tanhf(c);
  }
}

// ---------------- MFMA similarity GEMM (NT, bf16) + min/max ----------------
__global__ __launch_bounds__(256) void gemmnt_b(const unsigned short* __restrict__ fa,
                                                const unsigned short* __restrict__ fb,
                                                float* __restrict__ sc,
                                                unsigned* __restrict__ mmk)
{
  int t = threadIdx.x;
  int l = t & 63, w = t >> 6, b = l >> 4, m = l & 15;
  int rowbase = blockIdx.y*64 + w*16;
  int colbase = blockIdx.x*64;
  f4v acc[4];
  #pragma unroll
  for (int nt=0; nt<4; nt++) acc[nt] = (f4v){0,0,0,0};
  #pragma unroll
  for (int kt=0; kt<4; kt++){
    int arow = rowbase + m;
    s8v af = (s8v){0,0,0,0,0,0,0,0};
    if (arow < FFUNC) af = *(const s8v*)(fa + (size_t)arow*128 + kt*32 + b*8);
    #pragma unroll
    for (int nt=0; nt<4; nt++){
      int brow = colbase + nt*16 + m;
      s8v bf = (s8v){0,0,0,0,0,0,0,0};
      if (brow < FFUNC) bf = *(const s8v*)(fb + (size_t)brow*128 + kt*32 + b*8);
      acc[nt] = __builtin_amdgcn_mfma_f32_16x16x32_bf16(af, bf, acc[nt], 0, 0, 0);
    }
  }
  float mn = INFINITY, mx = -INFINITY;
  #pragma unroll
  for (int nt=0; nt<4; nt++){
    #pragma unroll
    for (int r2=0; r2<4; r2++){
      int row = rowbase + 4*b + r2;
      int col = colbase + nt*16 + m;
      if (row < FFUNC && col < FFUNC){
        float v = acc[nt][r2];
        sc[(size_t)row*FFUNC + col] = v;
        mn = fminf(mn, v); mx = fmaxf(mx, v);
      }
    }
  }
  __shared__ float smn[256], smx[256];
  smn[t]=mn; smx[t]=mx; __syncthreads();
  for (int o=128;o>0;o>>=1){
    if (t<o){ smn[t]=fminf(smn[t],smn[t+o]); smx[t]=fmaxf(smx[t],smx[t+o]); }
    __syncthreads();
  }
  if (t==0){ atomicMin(&mmk[0], fkey(smn[0])); atomicMax(&mmk[1], fkey(smx[0])); }
}

__global__ void hist_init_k(unsigned* mmk, unsigned* hist){
  int t = threadIdx.x;
  if (t==0){ mmk[0]=0xFFFFFFFFu; mmk[1]=0u; }
  if (t<16) hist[t]=0u;
}

__global__ void hist_k(const float* __restrict__ sc, const unsigned* __restrict__ mmk,
                       unsigned* __restrict__ hist)
{
  __shared__ unsigned hl[16];
  int t = threadIdx.x;
  if (t < 16) hl[t] = 0;
  __syncthreads();
  float mn = funkey(mmk[0]), mx = funkey(mmk[1]);
  float rng = fmaxf(mx - mn, 1e-12f);
  const long total = (long)FFUNC*FFUNC;
  for (long idx = (long)blockIdx.x*256 + t; idx < total; idx += (long)gridDim.x*256){
    float v = sc[idx];
    int b = (int)floorf((v - mn)/rng * 16.0f);
    b = min(max(b,0),15);
    atomicAdd(&hl[b], 1u);
  }
  __syncthreads();
  if (t < 16) atomicAdd(&hist[t], hl[t]);
}

// ---------------- final head ----------------
__global__ __launch_bounds__(256) void final_k(
    const float* __restrict__ p1, const float* __restrict__ p2,
    const float* __restrict__ Wtn, const float* __restrict__ Vtn,
    const float* __restrict__ btn, const unsigned* __restrict__ hist,
    const float* __restrict__ Wfc1, const float* __restrict__ bfc1,
    const float* __restrict__ Wsc, const float* __restrict__ bsc,
    float* __restrict__ outp)
{
  __shared__ float P1[128], P2[128], part[256], feats[32], hv[16];
  int t = threadIdx.x;
  if (t < 128){ P1[t] = p1[t]; P2[t] = p2[t]; }
  __syncthreads();
  int k = t & 15, pr_ = t >> 4;
  float acc = 0;
  for (int i = pr_*8; i < pr_*8+8; ++i){
    float pi = P1[i];
    const float* wrow = Wtn + ((size_t)i*128)*16 + k;
    float a2 = 0;
    for (int j=0;j<128;++j) a2 += P2[j]*wrow[(size_t)j*16];
    acc += pi*a2;
  }
  part[t] = acc;
  __syncthreads();
  if (t < 16){
    float sc_ = 0;
    for (int p=0;p<16;p++) sc_ += part[p*16 + t];
    float bl = btn[t];
    for (int j=0;j<256;j++) bl += Vtn[(size_t)t*256 + j] * (j<128 ? P1[j] : P2[j-128]);
    float tv = sc_ + bl;
    feats[t] = tv > 0.f ? tv : 0.f;
    feats[16+t] = (float)hist[t] * (1.0f/((float)FFUNC*(float)FFUNC));
  }
  __syncthreads();
  if (t < 16){
    float a2 = bfc1[t];
    for (int q2=0;q2<32;q2++) a2 += feats[q2]*Wfc1[q2*16 + t];
    hv[t] = a2 > 0.f ? a2 : 0.f;
  }
  __syncthreads();
  if (t == 0){
    float z = bsc[0];
    for (int m=0;m<16;m++) z += hv[m]*Wsc[m];
    outp[0] = sigf(z);
  }
}

// ---------------- host ----------------
extern "C" void kernel_launch(void* const* d_in, const int* in_sizes, int n_in,
                              void* d_out, int out_size, void* d_ws, size_t ws_size,
                              hipStream_t stream)
{
  (void)n_in; (void)out_size; (void)ws_size;
  const float* Wk = (const float*)d_in[16];
  const float* bk = (const float*)d_in[17];
  const float* Wq = (const float*)d_in[18];
  const float* bq = (const float*)d_in[19];
  const float* Wv = (const float*)d_in[20];
  const float* bv = (const float*)d_in[21];
  const float* Wa = (const float*)d_in[22];
  const float* ba = (const float*)d_in[23];
  const float* SKp = (const float*)d_in[24];
  const float* AR = (const float*)d_in[25];
  const float* MRm = (const float*)d_in[26];
  const float* PRp = (const float*)d_in[27];
  const float* WATT = (const float*)d_in[28];
  const float* WTN = (const float*)d_in[29];
  const float* VTN = (const float*)d_in[30];
  const float* BTN = (const float*)d_in[31];
  const float* WFC1 = (const float*)d_in[32];
  const float* BFC1 = (const float*)d_in[33];
  const float* WSC = (const float*)d_in[34];
  const float* BSC = (const float*)d_in[35];

  int NdA[2] = { in_sizes[0]/128, in_sizes[8]/128 };
  int NiA[2] = { in_sizes[1]/128, in_sizes[9]/128 };
  int EA[2][4];
  for (int g=0; g<2; g++)
    for (int r=0; r<4; r++) EA[g][r] = in_sizes[g*8+2+r]/2;

  int NdM = NdA[0] > NdA[1] ? NdA[0] : NdA[1];
  int NiM = NiA[0] > NiA[1] ? NiA[0] : NiA[1];
  long EtotM = 0;
  for (int g=0; g<2; g++){
    long et = 0; for (int r=0;r<4;r++) et += EA[g][r];
    if (et > EtotM) EtotM = et;
  }
  size_t nrowsM = (size_t)NdM + (size_t)NiM;
  int NOR = (int)(((nrowsM + 2 + 63)/64)*64);
  long KR4rows = 3L*NiM + NdM;

  char* wp = (char*)d_ws;
  auto alloc = [&](size_t bytes)->void*{
    void* p = (void*)wp;
    wp += (bytes + 255) & ~(size_t)255;
    return p;
  };
  unsigned short* Xb   = (unsigned short*)alloc(nrowsM*128*2);
  unsigned short* AGGb = (unsigned short*)alloc(nrowsM*128*2);
  float*          DEN  = (float*)alloc(nrowsM*4*4);
  unsigned short* O1b  = (unsigned short*)alloc(nrowsM*128*2);
  unsigned short* Qb   = (unsigned short*)alloc(nrowsM*128*2);
  unsigned short* KRK  = (unsigned short*)alloc((size_t)KR4rows*128*2);
  unsigned short* KRV  = (unsigned short*)alloc((size_t)KR4rows*128*2);
  int*            OFFS3= (int*)alloc((size_t)3*NOR*4);   // dir0, dir1, func
  int*            PERM = (int*)alloc((size_t)2*EtotM*4);
  int*            FPERM= (int*)alloc(nrowsM*4);
  int*            PART = (int*)alloc((size_t)3*1024*4);
  float*          GS[2];
  GS[0] = (float*)alloc((size_t)257280*4);
  GS[1] = (float*)alloc((size_t)257280*4);
  unsigned short* FB[2];
  FB[0] = (unsigned short*)alloc((size_t)FFUNC*128*2);
  FB[1] = (unsigned short*)alloc((size_t)FFUNC*128*2);
  unsigned*       MM   = (unsigned*)alloc(2*4);
  unsigned*       HIST = (unsigned*)alloc(16*4);
  unsigned short* WQP  = (unsigned short*)alloc((size_t)8*16384*2);
  unsigned short* WAP  = (unsigned short*)alloc((size_t)8*16384*2);
  unsigned short* WATTP= (unsigned short*)alloc((size_t)16384*2);
  unsigned short* COMPX= (unsigned short*)alloc((size_t)64*16384*2);  // 32 K + 32 V composites
  float*          BCX  = (float*)alloc((size_t)64*128*4);
  size_t uni_bytes = (size_t)FFUNC*FFUNC*4;
  size_t curs_bytes = (size_t)3*NOR*4;
  void* UNI = alloc(uni_bytes > curs_bytes ? uni_bytes : curs_bytes);
  int*   CURS3 = (int*)UNI;
  float* SCb   = (float*)UNI;

  packw_k<<<8,256,0,stream>>>(Wq, WQP);
  packw_k<<<8,256,0,stream>>>(Wa, WAP);
  packw_k<<<1,256,0,stream>>>(WATT, WATTP);
  comp_k<<<64,256,0,stream>>>(Wk, bk, Wv, bv, AR, MRm, COMPX, BCX);

  const size_t OF_FSUM=0, OF_FCNT=128000, OF_CF=129024, OF_ATTC=257024, OF_POOL=257152;
  const int stf[4] = {1,0,1,1};
  const int dtf[4] = {1,1,0,1};

  for (int g=0; g<2; ++g){
    int nd = NdA[g], ni = NiA[g];
    int nrows = nd + ni;
    int E[4] = {EA[g][0],EA[g][1],EA[g][2],EA[g][3]};
    const int* ei[4] = {(const int*)d_in[g*8+2], (const int*)d_in[g*8+3],
                        (const int*)d_in[g*8+4], (const int*)d_in[g*8+5]};
    const int* fdp = (const int*)d_in[g*8+6];
    const int* fip = (const int*)d_in[g*8+7];
    const float* x0d = (const float*)d_in[g*8+0];
    const float* x0i = (const float*)d_in[g*8+1];
    int gbd = (nd+63)/64, gbi = (ni+63)/64;
    int nb = gbd + gbi;
    int ntb = (nrows+255)/256; if (ntb > 2048) ntb = 2048;

    int koff[2][4], stA[2][4], dtA[2][4];
    for (int c=0;c<2;c++){
      int run = 0;
      for (int r=0;r<4;r++){
        stA[c][r] = (c==0) ? stf[r] : dtf[r];
        dtA[c][r] = (c==0) ? dtf[r] : stf[r];
        koff[c][r] = run;
        run += stA[c][r] ? ni : nd;
      }
    }

    // ---- build 2 merged edge CSRs + function CSR ----
    hipMemsetAsync(OFFS3, 0, (size_t)3*NOR*4, stream);
    HD hd; int hb = 0;
    for (int c2=0; c2<2; c2++)
      for (int r=0; r<4; r++){
        int ent = c2*4 + r;
        hd.blk0[ent] = hb;
        hd.dst[ent] = (c2==0) ? ei[r]+E[r] : ei[r];
        hd.src[ent] = (c2==0) ? ei[r] : ei[r]+E[r];
        hd.E[ent] = E[r];
        hd.cnto[ent] = c2*NOR + (dtA[c2][r] ? nd : 0);
        hd.permo[ent] = c2*(int)EtotM;
        hb += (E[r]+255)/256;
      }
    hd.blk0[8] = hb;
    csr_hist_all_k<<<hb,256,0,stream>>>(hd, OFFS3);
    fhist_k<<<ntb,256,0,stream>>>(fdp, fip, nd, ni, OFFS3 + (size_t)2*NOR);
    ScanDesc sd; sd.n[0] = nrows; sd.n[1] = nrows; sd.n[2] = FFUNC;
    int maxtiles = (nrows + 1023)/1024; if (maxtiles < 1) maxtiles = 1;
    dim3 sgrid(maxtiles, 3);
    scan_p1<<<sgrid,1024,0,stream>>>(sd, OFFS3, PART, NOR, maxtiles);
    scan_p2<<<1,1024,0,stream>>>(PART, maxtiles, 3);
    scan_p3<<<sgrid,1024,0,stream>>>(sd, OFFS3, CURS3, PART, NOR, maxtiles);
    csr_fill_all_k<<<hb,256,0,stream>>>(hd, CURS3, PERM);
    ffill_k<<<ntb,256,0,stream>>>(fdp, fip, nd, ni, CURS3 + (size_t)2*NOR, FPERM);

    for (int l=0; l<2; ++l){
      const void* xd = (l==0) ? (const void*)x0d : (const void*)Xb;
      const void* xi = (l==0) ? (const void*)x0i : (const void*)(Xb + (size_t)nd*128);
      int af32 = (l==0);
      for (int c=0; c<2; ++c){
        int pc = l*2 + c;
        // build output descriptor sets (data / inst)
        KSet kd, ki;
        kd.nout = 1; ki.nout = 1;
        kd.o[0].w = WQP + (size_t)(pc*2+0)*16384;
        kd.o[0].bi = bq + (size_t)(pc*2+0)*128;
        kd.o[0].dst = Qb;
        ki.o[0].w = WQP + (size_t)(pc*2+1)*16384;
        ki.o[0].bi = bq + (size_t)(pc*2+1)*128;
        ki.o[0].dst = Qb + (size_t)nd*128;
        for (int r=0;r<4;r++){
          int cid = (pc*2+c)*4 + r;
          KSet& ks = stA[c][r] ? ki : kd;
          ks.o[ks.nout].w = COMPX + (size_t)cid*16384;
          ks.o[ks.nout].bi = BCX + (size_t)cid*128;
          ks.o[ks.nout].dst = KRK + (size_t)koff[c][r]*128;
          ks.nout++;
          ks.o[ks.nout].w = COMPX + (size_t)(32+cid)*16384;
          ks.o[ks.nout].bi = BCX + (size_t)(32+cid)*128;
          ks.o[ks.nout].dst = KRV + (size_t)koff[c][r]*128;
          ks.nout++;
        }
        gemm_kqvc_k<<<nb,256,0,stream>>>(xd, xi, af32, nd, ni, gbd, kd, ki);
        MD md;
        for (int r=0;r<4;r++) md.koff[r] = koff[c][r];
        int eblk = (nrows*32 + 255)/256;
        e12m_k<<<eblk,256,0,stream>>>(KRK, KRV, Qb,
                                      OFFS3 + (size_t)c*NOR, PERM + (size_t)c*EtotM, nrows,
                                      PRp + (size_t)pc*16, AGGb, DEN, md);
        gemm_epi_k<<<nb,256,0,stream>>>(
            AGGb, DEN, nd, ni, gbd,
            WAP+(size_t)pc*2*16384, ba+(size_t)pc*2*128,
            xd, xi, af32,
            (c==1) ? O1b : (const unsigned short*)nullptr,
            (c==0) ? O1b : Xb,
            SKp + (size_t)pc*2, (c==0) ? 2 : 3);
      }
    }
    // pooling (function-CSR, bf16 X)
    float* fsum = GS[g]+OF_FSUM;  float* fcnt = GS[g]+OF_FCNT;
    float* cf   = GS[g]+OF_CF;    float* attc = GS[g]+OF_ATTC;
    float* pool = GS[g]+OF_POOL;
    hipMemsetAsync(pool, 0, 128*4, stream);
    f1c_k<<<FFUNC,256,0,stream>>>(Xb, OFFS3 + (size_t)2*NOR, FPERM, fsum, fcnt);
    attc2_k<<<1,1024,0,stream>>>(fsum, 1.0f/(float)nrows, WATT, attc);
    gemmb_k<<<(FFUNC+63)/64,256,0,stream>>>(fsum, FFUNC, WATTP, nullptr, cf, 1, fcnt);
    f23c_k<<<FFUNC,256,0,stream>>>(Xb, OFFS3 + (size_t)2*NOR, FPERM, cf, attc, FB[g], pool);
  }
  // similarity histogram + final head
  hist_init_k<<<1,32,0,stream>>>(MM, HIST);
  dim3 gnt((FFUNC+63)/64, (FFUNC+63)/64);
  gemmnt_b<<<gnt,256,0,stream>>>(FB[0], FB[1], SCb, MM);
  hist_k<<<512,256,0,stream>>>(SCb, MM, HIST);
  final_k<<<1,256,0,stream>>>(GS[0]+OF_POOL, GS[1]+OF_POOL, WTN, VTN, BTN, HIST,
                              WFC1, BFC1, WSC, BSC, (float*)d_out);
}

// Round 16
// 1564.609 us; speedup vs baseline: 1.2496x; 1.0264x over previous
//
#include <hip/hip_runtime.h>
#include <math.h>

#define FFUNC 1000

typedef __attribute__((ext_vector_type(8))) short s8v;
typedef __attribute__((ext_vector_type(4))) float f4v;

// ---------------- device helpers ----------------
__device__ __forceinline__ float sigf(float x){ return 1.0f/(1.0f+__expf(-x)); }
__device__ __forceinline__ float geluf(float x){
  float u = 1.5957691216057308f * (x + 0.044715f*x*x*x);
  return x / (1.0f + __expf(-u));
}
__device__ __forceinline__ unsigned fkey(float f){
  unsigned u = __float_as_uint(f);
  return (u & 0x80000000u) ? ~u : (u | 0x80000000u);
}
__device__ __forceinline__ float funkey(unsigned k){
  unsigned u = (k & 0x80000000u) ? (k ^ 0x80000000u) : ~k;
  return __uint_as_float(u);
}
__device__ __forceinline__ void atomAddF(float* p, float v){ unsafeAtomicAdd(p, v); }
__device__ __forceinline__ unsigned short bfr(float x){   // f32 -> bf16 RNE
  unsigned u = __float_as_uint(x);
  unsigned r = (u + 0x7FFFu + ((u >> 16) & 1u)) >> 16;
  return (unsigned short)r;
}
__device__ __forceinline__ float b2f(unsigned short v){
  return __uint_as_float((unsigned)v << 16);
}

// ---------------- weight prepack (Wq, Wa, Watt only) ----------------
__global__ void packw_k(const float* __restrict__ W, unsigned short* __restrict__ out){
  int mat = blockIdx.x;
  const float* w = W + (size_t)mat*16384;
  unsigned short* o = out + (size_t)mat*16384;
  for (int u=0; u<64; u++){
    int oi = u*256 + threadIdx.x;
    int j = oi & 7, l = (oi>>3) & 63, nt = (oi>>9) & 7, kt = oi >> 12;
    float v = w[(size_t)(kt*32 + 8*(l>>4) + j)*128 + nt*16 + (l&15)];
    o[oi] = bfr(v);
  }
}

// ---------------- composite weight precompute (parallelized: 64 mats x 8 u-chunks) ----------------
__global__ __launch_bounds__(256) void comp_k(
    const float* __restrict__ Wk, const float* __restrict__ bk,
    const float* __restrict__ Wv, const float* __restrict__ bv,
    const float* __restrict__ AR, const float* __restrict__ MR,
    unsigned short* __restrict__ OC, float* __restrict__ OB)
{
  const int stf[4]={1,0,1,1}, dtf[4]={1,1,0,1};
  int bb = blockIdx.x;
  int b = bb >> 3, uc = bb & 7;
  int kv = b>>5, idx = b&31, pcc = idx>>2, r = idx&3;
  int pc = pcc>>1, c = pcc&1;
  int styp = (c==0) ? stf[r] : dtf[r];
  const float* W  = (kv ? Wv : Wk) + (size_t)(pc*2+styp)*16384;
  const float* bi = (kv ? bv : bk) + (size_t)(pc*2+styp)*128;
  const float* a  = (kv ? MR : AR) + (size_t)(pc*4+r)*4096;
  unsigned short* oc = OC + (size_t)b*16384;
  float* ob = OB + (size_t)b*128;
  __shared__ float as[4096];
  for (int i=threadIdx.x; i<4096; i+=256) as[i] = a[i];
  __syncthreads();
  for (int u=uc*8; u<uc*8+8; u++){
    int oi = u*256 + threadIdx.x;
    int j = oi&7, l = (oi>>3)&63, nt = (oi>>9)&7, kt = oi>>12;
    int k = kt*32 + 8*(l>>4) + j;
    int col = nt*16 + (l&15);
    int h = col>>5, f = col&31;
    const float* wr = W + (size_t)k*128 + h*32;
    const float* ap = as + h*1024 + f;
    float s = 0;
    #pragma unroll 8
    for (int d=0; d<32; d++) s += wr[d]*ap[d*32];
    oc[oi] = bfr(s);
  }
  if (uc == 0 && threadIdx.x < 128){
    int col = threadIdx.x, h = col>>5, f = col&31;
    float s = 0;
    for (int d=0; d<32; d++) s += bi[h*32+d]*as[h*1024 + d*32 + f];
    ob[col] = s;
  }
}

// ---------------- multi-output projection GEMM (composite weights) ----------------
struct OutD { const unsigned short* w; const float* bi; unsigned short* dst; };
struct KSet { int nout; OutD o[7]; };
__global__ __launch_bounds__(256) void gemm_kqvc_k(
    const void* __restrict__ xdv, const void* __restrict__ xiv, int af32,
    int nd, int ni, int gbd, KSet kd, KSet ki)
{
  __shared__ __align__(16) unsigned short tile[2][64*128];
  int blk = blockIdx.x;
  int ty = (blk >= gbd);
  int N = ty ? ni : nd;
  int rbase = (ty ? (blk - gbd) : blk) * 64;
  const float* Af = (const float*)(ty ? xiv : xdv);
  const unsigned short* Ab = (const unsigned short*)(ty ? xiv : xdv);

  int t = threadIdx.x;
  int l = t & 63, w = t >> 6, b = l >> 4, m = l & 15;
  int arow = rbase + w*16 + m;
  bool rv = arow < N;

  // input A-fragments, held across all outputs
  s8v axf[4];
  #pragma unroll
  for (int kt=0; kt<4; kt++){
    s8v af = (s8v){0,0,0,0,0,0,0,0};
    if (rv){
      if (af32){
        const float* ap = Af + (size_t)arow*128 + kt*32 + b*8;
        float4 x0 = *(const float4*)ap;
        float4 x1 = *(const float4*)(ap + 4);
        af[0]=(short)bfr(x0.x); af[1]=(short)bfr(x0.y); af[2]=(short)bfr(x0.z); af[3]=(short)bfr(x0.w);
        af[4]=(short)bfr(x1.x); af[5]=(short)bfr(x1.y); af[6]=(short)bfr(x1.z); af[7]=(short)bfr(x1.w);
      } else {
        af = *(const s8v*)(Ab + (size_t)arow*128 + kt*32 + b*8);
      }
    }
    axf[kt] = af;
  }

  int nout = ty ? ki.nout : kd.nout;
  int cur = 0;
  for (int i=0; i<nout; i++){
    const unsigned short* wp = ty ? ki.o[i].w   : kd.o[i].w;
    const float*          bi = ty ? ki.o[i].bi  : kd.o[i].bi;
    unsigned short*      dst = ty ? ki.o[i].dst : kd.o[i].dst;
    f4v acc[8];
    #pragma unroll
    for (int nt=0; nt<8; nt++) acc[nt] = (f4v){0,0,0,0};
    #pragma unroll
    for (int kt=0; kt<4; kt++)
      #pragma unroll
      for (int nt=0; nt<8; nt++){
        s8v bf = *(const s8v*)(wp + ((kt*8 + nt)*64 + l)*8);
        acc[nt] = __builtin_amdgcn_mfma_f32_16x16x32_bf16(axf[kt], bf, acc[nt], 0, 0, 0);
      }
    // stage (bias added) into swizzled tile[cur]
    #pragma unroll
    for (int r2=0; r2<4; r2++){
      int trow = w*16 + 4*b + r2;
      #pragma unroll
      for (int nt=0; nt<8; nt++){
        int col = nt*16 + m;
        int ch = (col>>3) ^ (trow&15);
        tile[cur][trow*128 + ch*8 + (col&7)] = bfr(acc[nt][r2] + bi[col]);
      }
    }
    __syncthreads();
    // wide store
    #pragma unroll
    for (int it=0; it<4; it++){
      int idx = it*256 + t;
      int rr = idx >> 4, cc = idx & 15;
      int orow = rbase + rr;
      if (orow < N)
        *(uint4*)(dst + (size_t)orow*128 + cc*8) =
            *(const uint4*)(&tile[cur][rr*128 + ((cc ^ (rr&15))*8)]);
    }
    cur ^= 1;
  }
}

// ---------------- fused epilogue GEMM (LDS-staged wide epilogue) ----------------
__global__ __launch_bounds__(256) void gemm_epi_k(
    const unsigned short* __restrict__ AGGb, const float* __restrict__ DENb,
    int nd, int ni, int gbd,
    const unsigned short* __restrict__ WA, const float* __restrict__ bA,
    const void* __restrict__ xin_dv, const void* __restrict__ xin_iv, int xf32,
    const unsigned short* __restrict__ o1p, unsigned short* __restrict__ out,
    const float* __restrict__ skp, int mode)
{
  __shared__ __align__(16) float ftile[64*128];
  int blk = blockIdx.x;
  int ty = (blk >= gbd);
  int N = ty ? ni : nd;
  int rbase = (ty ? (blk - gbd) : blk) * 64;
  int goff = ty ? nd : 0;
  const unsigned short* wa = WA + (ty ? 16384 : 0);
  const float* ba2 = bA + (ty ? 128 : 0);
  const float* xinF = (const float*)(ty ? xin_iv : xin_dv);
  const unsigned short* xinB = (const unsigned short*)(ty ? xin_iv : xin_dv);
  float s = sigf(skp[ty]), s1 = 1.0f - s;

  int t = threadIdx.x;
  int l = t & 63, w = t >> 6, b = l >> 4, m = l & 15;
  int arow = rbase + w*16 + m;
  bool rv = arow < N;
  f4v acc[8];
  #pragma unroll
  for (int nt=0; nt<8; nt++) acc[nt] = (f4v){0,0,0,0};

  float4 dv4 = make_float4(1.f,1.f,1.f,1.f);
  if (rv){
    size_t grow = (size_t)(goff + arow);
    float4 dr = *(const float4*)(DENb + grow*4);
    dv4.x = 1.0f / fmaxf(dr.x, 1e-16f);
    dv4.y = 1.0f / fmaxf(dr.y, 1e-16f);
    dv4.z = 1.0f / fmaxf(dr.z, 1e-16f);
    dv4.w = 1.0f / fmaxf(dr.w, 1e-16f);
  }
  #pragma unroll
  for (int kt=0; kt<4; kt++){
    s8v af = (s8v){0,0,0,0,0,0,0,0};
    if (rv){
      size_t grow = (size_t)(goff + arow);
      float dv = (kt==0)?dv4.x:(kt==1)?dv4.y:(kt==2)?dv4.z:dv4.w;
      s8v ag = *(const s8v*)(AGGb + grow*128 + kt*32 + b*8);
      #pragma unroll
      for (int jj=0; jj<8; jj++)
        af[jj] = (short)bfr(geluf(b2f((unsigned short)ag[jj]) * dv));
    }
    #pragma unroll
    for (int nt=0; nt<8; nt++){
      s8v bf = *(const s8v*)(wa + ((kt*8 + nt)*64 + l)*8);
      acc[nt] = __builtin_amdgcn_mfma_f32_16x16x32_bf16(af, bf, acc[nt], 0, 0, 0);
    }
  }
  // stage f32 acc into swizzled tile
  #pragma unroll
  for (int r2=0; r2<4; r2++){
    int trow = w*16 + 4*b + r2;
    #pragma unroll
    for (int nt=0; nt<8; nt++){
      int col = nt*16 + m;
      int ch = (col>>2) ^ (trow&31);
      ftile[trow*128 + ch*4 + (col&3)] = acc[nt][r2];
    }
  }
  __syncthreads();
  // wide epilogue: bias + skip (+combine) + store
  #pragma unroll
  for (int it=0; it<8; it++){
    int idx = it*256 + t;          // row*32 + chunk
    int rr = idx >> 5, cc = idx & 31;
    int orow = rbase + rr;
    if (orow >= N) continue;
    size_t grow = (size_t)(goff + orow);
    float4 a4 = *(const float4*)(&ftile[rr*128 + ((cc ^ (rr&31))*4)]);
    float4 b4 = *(const float4*)(ba2 + cc*4);
    float xv0, xv1, xv2, xv3;
    if (xf32){
      float4 x4 = *(const float4*)(xinF + (size_t)orow*128 + cc*4);
      xv0=x4.x; xv1=x4.y; xv2=x4.z; xv3=x4.w;
    } else {
      ushort4 x4 = *(const ushort4*)(xinB + (size_t)orow*128 + cc*4);
      xv0=b2f(x4.x); xv1=b2f(x4.y); xv2=b2f(x4.z); xv3=b2f(x4.w);
    }
    float v0 = s*(a4.x + b4.x) + s1*xv0;
    float v1 = s*(a4.y + b4.y) + s1*xv1;
    float v2 = s*(a4.z + b4.z) + s1*xv2;
    float v3 = s*(a4.w + b4.w) + s1*xv3;
    if (mode == 3){
      ushort4 o4 = *(const ushort4*)(o1p + grow*128 + cc*4);
      v0 = fmaxf(0.5f*b2f(o4.x) + 0.5f*v0, 0.f);
      v1 = fmaxf(0.5f*b2f(o4.y) + 0.5f*v1, 0.f);
      v2 = fmaxf(0.5f*b2f(o4.z) + 0.5f*v2, 0.f);
      v3 = fmaxf(0.5f*b2f(o4.w) + 0.5f*v3, 0.f);
    }
    *(ushort4*)(out + grow*128 + cc*4) =
        make_ushort4(bfr(v0), bfr(v1), bfr(v2), bfr(v3));
  }
}

// ---------------- merged CSR build ----------------
struct ScanDesc { int n[8]; };

struct HD {
  int blk0[9];
  const int* dst[8];
  const int* src[8];
  int E[8];
  int cnto[8];
  int permo[8];
};
__global__ void csr_hist_all_k(HD d, int* __restrict__ cnt){
  int b = blockIdx.x;
  int r = 0;
  while (r < 7 && b >= d.blk0[r+1]) r++;
  int e = (b - d.blk0[r])*256 + threadIdx.x;
  if (e < d.E[r]) atomicAdd(&cnt[d.cnto[r] + d.dst[r][e]], 1);
}
__global__ void csr_fill_all_k(HD d, int* __restrict__ curs, int* __restrict__ perm){
  int b = blockIdx.x;
  int r = 0;
  while (r < 7 && b >= d.blk0[r+1]) r++;
  int e = (b - d.blk0[r])*256 + threadIdx.x;
  if (e < d.E[r]){
    int pos = atomicAdd(&curs[d.cnto[r] + d.dst[r][e]], 1);
    perm[d.permo[r] + pos] = d.src[r][e] | ((r & 3) << 24);
  }
}

// ---------------- parallel 3-phase scan ----------------
__global__ __launch_bounds__(1024) void scan_p1(ScanDesc sd, const int* __restrict__ offs,
                                                int* __restrict__ part, int NO, int MAXT){
  int ent = blockIdx.y, tile = blockIdx.x;
  int n = sd.n[ent];
  int i = tile*1024 + threadIdx.x;
  int v = (i < n) ? offs[(size_t)ent*NO + i] : 0;
  #pragma unroll
  for (int d2=1; d2<64; d2<<=1) v += __shfl_xor(v, d2, 64);
  __shared__ int ws_[16];
  int lane = threadIdx.x & 63, wv = threadIdx.x >> 6;
  if (lane == 0) ws_[wv] = v;
  __syncthreads();
  if (threadIdx.x == 0){
    int s = 0;
    #pragma unroll
    for (int k=0;k<16;k++) s += ws_[k];
    part[ent*MAXT + tile] = s;
  }
}

__global__ __launch_bounds__(1024) void scan_p2(int* __restrict__ part, int MAXT, int nent){
  int tid = threadIdx.x, lane = tid & 63, wv = tid >> 6;
  __shared__ int wsum[16];
  __shared__ int woff[17];
  for (int ent=0; ent<nent; ent++){
    int v = (tid < MAXT) ? part[ent*MAXT + tid] : 0;
    int s = v;
    #pragma unroll
    for (int d2=1; d2<64; d2<<=1){
      int t2 = __shfl_up(s, d2, 64);
      if (lane >= d2) s += t2;
    }
    if (lane == 63) wsum[wv] = s;
    __syncthreads();
    if (wv == 0 && lane < 16){
      int x = wsum[lane];
      #pragma unroll
      for (int d2=1; d2<16; d2<<=1){
        int t2 = __shfl_up(x, d2, 64);
        if (lane >= d2) x += t2;
      }
      woff[lane+1] = x;
      if (lane == 0) woff[0] = 0;
    }
    __syncthreads();
    if (tid < MAXT) part[ent*MAXT + tid] = woff[wv] + s - v;
    __syncthreads();
  }
}

__global__ __launch_bounds__(1024) void scan_p3(ScanDesc sd, int* __restrict__ offs,
                                                int* __restrict__ curs,
                                                const int* __restrict__ part, int NO, int MAXT){
  int ent = blockIdx.y, tile = blockIdx.x;
  int n = sd.n[ent];
  int i = tile*1024 + threadIdx.x;
  int v = (i < n) ? offs[(size_t)ent*NO + i] : 0;
  int lane = threadIdx.x & 63, wv = threadIdx.x >> 6;
  int s = v;
  #pragma unroll
  for (int d2=1; d2<64; d2<<=1){
    int t2 = __shfl_up(s, d2, 64);
    if (lane >= d2) s += t2;
  }
  __shared__ int wsum[16];
  __shared__ int woff[17];
  if (lane == 63) wsum[wv] = s;
  __syncthreads();
  if (wv == 0 && lane < 16){
    int x = wsum[lane];
    #pragma unroll
    for (int d2=1; d2<16; d2<<=1){
      int t2 = __shfl_up(x, d2, 64);
      if (lane >= d2) x += t2;
    }
    woff[lane+1] = x;
    if (lane == 0) woff[0] = 0;
  }
  __syncthreads();
  int excl = part[ent*MAXT + tile] + woff[wv] + s - v;
  if (i < n){
    offs[(size_t)ent*NO + i] = excl;
    curs[(size_t)ent*NO + i] = excl;
  }
  if (i == n-1) offs[(size_t)ent*NO + n] = excl + v;
}

// ---------------- function-CSR build ----------------
__global__ void fhist_k(const int* __restrict__ fd, const int* __restrict__ fi,
                        int Nd, int Ni, int* __restrict__ cnt){
  int nt = Nd + Ni;
  for (int n = blockIdx.x*256 + threadIdx.x; n < nt; n += gridDim.x*256){
    int f = (n < Nd) ? fd[n] : fi[n-Nd];
    atomicAdd(&cnt[f], 1);
  }
}
__global__ void ffill_k(const int* __restrict__ fd, const int* __restrict__ fi,
                        int Nd, int Ni, int* __restrict__ curs, int* __restrict__ perm){
  int nt = Nd + Ni;
  for (int n = blockIdx.x*256 + threadIdx.x; n < nt; n += gridDim.x*256){
    int f = (n < Nd) ? fd[n] : fi[n-Nd];
    int pos = atomicAdd(&curs[f], 1);
    perm[pos] = n;
  }
}

// ---------------- E12 merged: online-softmax edge aggregation ----------------
struct MD { int koff[4]; };
__global__ __launch_bounds__(256) void e12m_k(
    const unsigned short* __restrict__ KRK, const unsigned short* __restrict__ KRV,
    const unsigned short* __restrict__ Qb,
    const int* __restrict__ offs, const int* __restrict__ perm, int nrows,
    const float* __restrict__ pr,
    unsigned short* __restrict__ aggb, float* __restrict__ den, MD md)
{
  int gidx = blockIdx.x*256 + threadIdx.x;
  int node = gidx >> 5; if (node >= nrows) return;
  int sub = gidx & 31, h = sub >> 3, j = sub & 7;
  int o0 = offs[node], o1 = offs[node+1];
  unsigned short* ap = aggb + (size_t)node*128 + h*32 + j*4;
  if (o0 == o1){
    *(ushort4*)ap = make_ushort4(0,0,0,0);
    if (j == 0) den[(size_t)node*4 + h] = 0.f;
    return;
  }
  ushort4 qa = *(const ushort4*)(Qb + (size_t)node*128 + h*32 + j*4);
  float q0=b2f(qa.x), q1=b2f(qa.y), q2=b2f(qa.z), q3=b2f(qa.w);
  float scl[4];
  #pragma unroll
  for (int r=0;r<4;r++) scl[r] = pr[r*4 + h] * 0.17677669529663687f;  // 1/sqrt(32)
  float mx = -INFINITY, ds = 0.f;
  float4 acc = make_float4(0.f,0.f,0.f,0.f);
  for (int i=o0; i<o1; ++i){
    int pk = perm[i];
    int src = pk & 0xFFFFFF, rel = pk >> 24;
    size_t rowo = (size_t)(md.koff[rel] + src)*128 + h*32 + j*4;
    ushort4 aa = *(const ushort4*)(KRK + rowo);
    ushort4 vv = *(const ushort4*)(KRV + rowo);
    float p = b2f(aa.x)*q0 + b2f(aa.y)*q1 + b2f(aa.z)*q2 + b2f(aa.w)*q3;
    p += __shfl_xor(p, 1, 8);
    p += __shfl_xor(p, 2, 8);
    p += __shfl_xor(p, 4, 8);
    float lg = p * scl[rel];
    float nm = fmaxf(mx, lg);
    float corr = __expf(mx - nm);
    float ev = __expf(lg - nm);
    acc.x = acc.x*corr + ev*b2f(vv.x);
    acc.y = acc.y*corr + ev*b2f(vv.y);
    acc.z = acc.z*corr + ev*b2f(vv.z);
    acc.w = acc.w*corr + ev*b2f(vv.w);
    ds = ds*corr + ev;
    mx = nm;
  }
  *(ushort4*)ap = make_ushort4(bfr(acc.x), bfr(acc.y), bfr(acc.z), bfr(acc.w));
  if (j == 0) den[(size_t)node*4 + h] = ds;
}

// ---------------- plain MFMA GEMM (cf only; optional per-row divide) ----------------
__global__ __launch_bounds__(256) void gemmb_k(
    const float* __restrict__ A, int N,
    const unsigned short* __restrict__ Wp, const float* __restrict__ bias,
    float* __restrict__ outf, int mode, const float* __restrict__ rdiv)
{
  int t = threadIdx.x;
  int l = t & 63, w = t >> 6, b = l >> 4, m = l & 15;
  int arow = blockIdx.x*64 + w*16 + m;
  bool rv = arow < N;
  float dv = 1.0f;
  if (rv && rdiv) dv = 1.0f / fmaxf(rdiv[arow], 1.0f);
  f4v acc[8];
  #pragma unroll
  for (int nt=0; nt<8; nt++) acc[nt] = (f4v){0,0,0,0};
  #pragma unroll
  for (int kt=0; kt<4; kt++){
    s8v af = (s8v){0,0,0,0,0,0,0,0};
    if (rv){
      const float* ap = A + (size_t)arow*128 + kt*32 + b*8;
      float4 x0 = *(const float4*)ap;
      float4 x1 = *(const float4*)(ap + 4);
      af[0]=(short)bfr(x0.x*dv); af[1]=(short)bfr(x0.y*dv); af[2]=(short)bfr(x0.z*dv); af[3]=(short)bfr(x0.w*dv);
      af[4]=(short)bfr(x1.x*dv); af[5]=(short)bfr(x1.y*dv); af[6]=(short)bfr(x1.z*dv); af[7]=(short)bfr(x1.w*dv);
    }
    #pragma unroll
    for (int nt=0; nt<8; nt++){
      s8v bf = *(const s8v*)(Wp + ((kt*8 + nt)*64 + l)*8);
      acc[nt] = __builtin_amdgcn_mfma_f32_16x16x32_bf16(af, bf, acc[nt], 0, 0, 0);
    }
  }
  #pragma unroll
  for (int r2=0; r2<4; r2++){
    int orow = blockIdx.x*64 + w*16 + 4*b + r2;
    if (orow >= N) continue;
    #pragma unroll
    for (int nt=0; nt<8; nt++){
      int col = nt*16 + m;
      float v = acc[nt][r2];
      if (bias) v += bias[col];
      if (mode == 1) v = tanhf(v);
      outf[(size_t)orow*128 + col] = v;
    }
  }
}

// ---------------- func pool (CSR, bf16 X): sums + counts ----------------
__global__ __launch_bounds__(256) void f1c_k(const unsigned short* __restrict__ X,
    const int* __restrict__ foffs, const int* __restrict__ fperm,
    float* __restrict__ fsum, float* __restrict__ fcnt)
{
  __shared__ __align__(16) float red[4][128];
  int t = threadIdx.x, wv = t >> 6, lane = t & 63;
  int f = blockIdx.x;
  int o0 = foffs[f], o1 = foffs[f+1];
  float a0 = 0, a1 = 0;
  for (int i = o0 + wv; i < o1; i += 4){
    ushort2 x = *(const ushort2*)(X + (size_t)fperm[i]*128 + lane*2);
    a0 += b2f(x.x); a1 += b2f(x.y);
  }
  red[wv][lane*2] = a0; red[wv][lane*2+1] = a1;
  __syncthreads();
  if (t < 128)
    fsum[(size_t)f*128 + t] = red[0][t] + red[1][t] + red[2][t] + red[3][t];
  if (t == 0) fcnt[f] = (float)(o1 - o0);
}

// ---------------- func pool (CSR, bf16 X): femb(bf16) + global attention pool ----------------
__global__ __launch_bounds__(256) void f23c_k(const unsigned short* __restrict__ X,
    const int* __restrict__ foffs, const int* __restrict__ fperm,
    const float* __restrict__ cf, const float* __restrict__ attc,
    unsigned short* __restrict__ fembb, float* __restrict__ pooled)
{
  __shared__ __align__(16) float rede[4][128];
  __shared__ __align__(16) float redp[4][128];
  int t = threadIdx.x, wv = t >> 6, lane = t & 63;
  int f = blockIdx.x;
  int o0 = foffs[f], o1 = foffs[f+1];
  float c0 = cf[(size_t)f*128 + lane*2], c1 = cf[(size_t)f*128 + lane*2 + 1];
  float t0 = attc[lane*2], t1 = attc[lane*2 + 1];
  float e0=0, e1=0, p0=0, p1=0;
  for (int i = o0 + wv; i < o1; i += 4){
    ushort2 xr = *(const ushort2*)(X + (size_t)fperm[i]*128 + lane*2);
    float vx = b2f(xr.x), vy = b2f(xr.y);
    union { double d; float2 f2; } u;
    u.f2.x = vx*c0 + vy*c1;
    u.f2.y = vx*t0 + vy*t1;
    #pragma unroll
    for (int m2=1; m2<64; m2<<=1){
      union { double d; float2 f2; } v;
      v.d = __shfl_xor(u.d, m2, 64);
      u.f2.x += v.f2.x; u.f2.y += v.f2.y;
    }
    float s1 = sigf(u.f2.x), s2 = sigf(u.f2.y);
    e0 += vx*s1; e1 += vy*s1;
    p0 += vx*s2; p1 += vy*s2;
  }
  rede[wv][lane*2] = e0; rede[wv][lane*2+1] = e1;
  redp[wv][lane*2] = p0; redp[wv][lane*2+1] = p1;
  __syncthreads();
  if (t < 128){
    fembb[(size_t)f*128 + t] = bfr(rede[0][t] + rede[1][t] + rede[2][t] + rede[3][t]);
    float pp = redp[0][t] + redp[1][t] + redp[2][t] + redp[3][t];
    atomAddF(&pooled[t], pp);
  }
}

// ---------------- attention-pool context (parallel colsum) ----------------
__global__ __launch_bounds__(1024) void attc2_k(const float* __restrict__ fsum, float Ninv,
                                                const float* __restrict__ Watt,
                                                float* __restrict__ attc)
{
  __shared__ float part[8][128];
  __shared__ float mean[128];
  int t = threadIdx.x;
  int j = t & 127, ch = t >> 7;
  float a = 0;
  for (int f = ch; f < FFUNC; f += 8) a += fsum[(size_t)f*128 + j];
  part[ch][j] = a;
  __syncthreads();
  if (t < 128){
    float m = 0;
    #pragma unroll
    for (int c=0;c<8;c++) m += part[c][t];
    mean[t] = m * Ninv;
  }
  __syncthreads();
  if (t < 128){
    float c = 0;
    for (int k=0;k<128;k++) c += mean[k]*Watt[(size_t)k*128 + t];
    attc[t] = tanhf(c);
  }
}

// ---------------- MFMA similarity GEMM (NT, bf16) + min/max ----------------
__global__ __launch_bounds__(256) void gemmnt_b(const unsigned short* __restrict__ fa,
                                                const unsigned short* __restrict__ fb,
                                                float* __restrict__ sc,
                                                unsigned* __restrict__ mmk)
{
  int t = threadIdx.x;
  int l = t & 63, w = t >> 6, b = l >> 4, m = l & 15;
  int rowbase = blockIdx.y*64 + w*16;
  int colbase = blockIdx.x*64;
  f4v acc[4];
  #pragma unroll
  for (int nt=0; nt<4; nt++) acc[nt] = (f4v){0,0,0,0};
  #pragma unroll
  for (int kt=0; kt<4; kt++){
    int arow = rowbase + m;
    s8v af = (s8v){0,0,0,0,0,0,0,0};
    if (arow < FFUNC) af = *(const s8v*)(fa + (size_t)arow*128 + kt*32 + b*8);
    #pragma unroll
    for (int nt=0; nt<4; nt++){
      int brow = colbase + nt*16 + m;
      s8v bf = (s8v){0,0,0,0,0,0,0,0};
      if (brow < FFUNC) bf = *(const s8v*)(fb + (size_t)brow*128 + kt*32 + b*8);
      acc[nt] = __builtin_amdgcn_mfma_f32_16x16x32_bf16(af, bf, acc[nt], 0, 0, 0);
    }
  }
  float mn = INFINITY, mx = -INFINITY;
  #pragma unroll
  for (int nt=0; nt<4; nt++){
    #pragma unroll
    for (int r2=0; r2<4; r2++){
      int row = rowbase + 4*b + r2;
      int col = colbase + nt*16 + m;
      if (row < FFUNC && col < FFUNC){
        float v = acc[nt][r2];
        sc[(size_t)row*FFUNC + col] = v;
        mn = fminf(mn, v); mx = fmaxf(mx, v);
      }
    }
  }
  __shared__ float smn[256], smx[256];
  smn[t]=mn; smx[t]=mx; __syncthreads();
  for (int o=128;o>0;o>>=1){
    if (t<o){ smn[t]=fminf(smn[t],smn[t+o]); smx[t]=fmaxf(smx[t],smx[t+o]); }
    __syncthreads();
  }
  if (t==0){ atomicMin(&mmk[0], fkey(smn[0])); atomicMax(&mmk[1], fkey(smx[0])); }
}

__global__ void hist_init_k(unsigned* mmk, unsigned* hist){
  int t = threadIdx.x;
  if (t==0){ mmk[0]=0xFFFFFFFFu; mmk[1]=0u; }
  if (t<16) hist[t]=0u;
}

__global__ void hist_k(const float* __restrict__ sc, const unsigned* __restrict__ mmk,
                       unsigned* __restrict__ hist)
{
  __shared__ unsigned hl[16];
  int t = threadIdx.x;
  if (t < 16) hl[t] = 0;
  __syncthreads();
  float mn = funkey(mmk[0]), mx = funkey(mmk[1]);
  float rng = fmaxf(mx - mn, 1e-12f);
  const long total = (long)FFUNC*FFUNC;
  for (long idx = (long)blockIdx.x*256 + t; idx < total; idx += (long)gridDim.x*256){
    float v = sc[idx];
    int b = (int)floorf((v - mn)/rng * 16.0f);
    b = min(max(b,0),15);
    atomicAdd(&hl[b], 1u);
  }
  __syncthreads();
  if (t < 16) atomicAdd(&hist[t], hl[t]);
}

// ---------------- final head ----------------
__global__ __launch_bounds__(256) void final_k(
    const float* __restrict__ p1, const float* __restrict__ p2,
    const float* __restrict__ Wtn, const float* __restrict__ Vtn,
    const float* __restrict__ btn, const unsigned* __restrict__ hist,
    const float* __restrict__ Wfc1, const float* __restrict__ bfc1,
    const float* __restrict__ Wsc, const float* __restrict__ bsc,
    float* __restrict__ outp)
{
  __shared__ float P1[128], P2[128], part[256], feats[32], hv[16];
  int t = threadIdx.x;
  if (t < 128){ P1[t] = p1[t]; P2[t] = p2[t]; }
  __syncthreads();
  int k = t & 15, pr_ = t >> 4;
  float acc = 0;
  for (int i = pr_*8; i < pr_*8+8; ++i){
    float pi = P1[i];
    const float* wrow = Wtn + ((size_t)i*128)*16 + k;
    float a2 = 0;
    for (int j=0;j<128;++j) a2 += P2[j]*wrow[(size_t)j*16];
    acc += pi*a2;
  }
  part[t] = acc;
  __syncthreads();
  if (t < 16){
    float sc_ = 0;
    for (int p=0;p<16;p++) sc_ += part[p*16 + t];
    float bl = btn[t];
    for (int j=0;j<256;j++) bl += Vtn[(size_t)t*256 + j] * (j<128 ? P1[j] : P2[j-128]);
    float tv = sc_ + bl;
    feats[t] = tv > 0.f ? tv : 0.f;
    feats[16+t] = (float)hist[t] * (1.0f/((float)FFUNC*(float)FFUNC));
  }
  __syncthreads();
  if (t < 16){
    float a2 = bfc1[t];
    for (int q2=0;q2<32;q2++) a2 += feats[q2]*Wfc1[q2*16 + t];
    hv[t] = a2 > 0.f ? a2 : 0.f;
  }
  __syncthreads();
  if (t == 0){
    float z = bsc[0];
    for (int m=0;m<16;m++) z += hv[m]*Wsc[m];
    outp[0] = sigf(z);
  }
}

// ---------------- host ----------------
extern "C" void kernel_launch(void* const* d_in, const int* in_sizes, int n_in,
                              void* d_out, int out_size, void* d_ws, size_t ws_size,
                              hipStream_t stream)
{
  (void)n_in; (void)out_size; (void)ws_size;
  const float* Wk = (const float*)d_in[16];
  const float* bk = (const float*)d_in[17];
  const float* Wq = (const float*)d_in[18];
  const float* bq = (const float*)d_in[19];
  const float* Wv = (const float*)d_in[20];
  const float* bv = (const float*)d_in[21];
  const float* Wa = (const float*)d_in[22];
  const float* ba = (const float*)d_in[23];
  const float* SKp = (const float*)d_in[24];
  const float* AR = (const float*)d_in[25];
  const float* MRm = (const float*)d_in[26];
  const float* PRp = (const float*)d_in[27];
  const float* WATT = (const float*)d_in[28];
  const float* WTN = (const float*)d_in[29];
  const float* VTN = (const float*)d_in[30];
  const float* BTN = (const float*)d_in[31];
  const float* WFC1 = (const float*)d_in[32];
  const float* BFC1 = (const float*)d_in[33];
  const float* WSC = (const float*)d_in[34];
  const float* BSC = (const float*)d_in[35];

  int NdA[2] = { in_sizes[0]/128, in_sizes[8]/128 };
  int NiA[2] = { in_sizes[1]/128, in_sizes[9]/128 };
  int EA[2][4];
  for (int g=0; g<2; g++)
    for (int r=0; r<4; r++) EA[g][r] = in_sizes[g*8+2+r]/2;

  int NdM = NdA[0] > NdA[1] ? NdA[0] : NdA[1];
  int NiM = NiA[0] > NiA[1] ? NiA[0] : NiA[1];
  long EtotM = 0;
  for (int g=0; g<2; g++){
    long et = 0; for (int r=0;r<4;r++) et += EA[g][r];
    if (et > EtotM) EtotM = et;
  }
  size_t nrowsM = (size_t)NdM + (size_t)NiM;
  int NOR = (int)(((nrowsM + 2 + 63)/64)*64);
  long KR4rows = 3L*NiM + NdM;

  char* wp = (char*)d_ws;
  auto alloc = [&](size_t bytes)->void*{
    void* p = (void*)wp;
    wp += (bytes + 255) & ~(size_t)255;
    return p;
  };
  unsigned short* Xb   = (unsigned short*)alloc(nrowsM*128*2);
  unsigned short* AGGb = (unsigned short*)alloc(nrowsM*128*2);
  float*          DEN  = (float*)alloc(nrowsM*4*4);
  unsigned short* O1b  = (unsigned short*)alloc(nrowsM*128*2);
  unsigned short* Qb   = (unsigned short*)alloc(nrowsM*128*2);
  unsigned short* KRK  = (unsigned short*)alloc((size_t)KR4rows*128*2);
  unsigned short* KRV  = (unsigned short*)alloc((size_t)KR4rows*128*2);
  int*            OFFS3= (int*)alloc((size_t)3*NOR*4);   // dir0, dir1, func
  int*            PERM = (int*)alloc((size_t)2*EtotM*4);
  int*            FPERM= (int*)alloc(nrowsM*4);
  int*            PART = (int*)alloc((size_t)3*1024*4);
  float*          GS[2];
  GS[0] = (float*)alloc((size_t)257280*4);
  GS[1] = (float*)alloc((size_t)257280*4);
  unsigned short* FB[2];
  FB[0] = (unsigned short*)alloc((size_t)FFUNC*128*2);
  FB[1] = (unsigned short*)alloc((size_t)FFUNC*128*2);
  unsigned*       MM   = (unsigned*)alloc(2*4);
  unsigned*       HIST = (unsigned*)alloc(16*4);
  unsigned short* WQP  = (unsigned short*)alloc((size_t)8*16384*2);
  unsigned short* WAP  = (unsigned short*)alloc((size_t)8*16384*2);
  unsigned short* WATTP= (unsigned short*)alloc((size_t)16384*2);
  unsigned short* COMPX= (unsigned short*)alloc((size_t)64*16384*2);  // 32 K + 32 V composites
  float*          BCX  = (float*)alloc((size_t)64*128*4);
  size_t uni_bytes = (size_t)FFUNC*FFUNC*4;
  size_t curs_bytes = (size_t)3*NOR*4;
  void* UNI = alloc(uni_bytes > curs_bytes ? uni_bytes : curs_bytes);
  int*   CURS3 = (int*)UNI;
  float* SCb   = (float*)UNI;

  packw_k<<<8,256,0,stream>>>(Wq, WQP);
  packw_k<<<8,256,0,stream>>>(Wa, WAP);
  packw_k<<<1,256,0,stream>>>(WATT, WATTP);
  comp_k<<<512,256,0,stream>>>(Wk, bk, Wv, bv, AR, MRm, COMPX, BCX);

  const size_t OF_FSUM=0, OF_FCNT=128000, OF_CF=129024, OF_ATTC=257024, OF_POOL=257152;
  const int stf[4] = {1,0,1,1};
  const int dtf[4] = {1,1,0,1};

  for (int g=0; g<2; ++g){
    int nd = NdA[g], ni = NiA[g];
    int nrows = nd + ni;
    int E[4] = {EA[g][0],EA[g][1],EA[g][2],EA[g][3]};
    const int* ei[4] = {(const int*)d_in[g*8+2], (const int*)d_in[g*8+3],
                        (const int*)d_in[g*8+4], (const int*)d_in[g*8+5]};
    const int* fdp = (const int*)d_in[g*8+6];
    const int* fip = (const int*)d_in[g*8+7];
    const float* x0d = (const float*)d_in[g*8+0];
    const float* x0i = (const float*)d_in[g*8+1];
    int gbd = (nd+63)/64, gbi = (ni+63)/64;
    int nb = gbd + gbi;
    int ntb = (nrows+255)/256; if (ntb > 2048) ntb = 2048;

    int koff[2][4], stA[2][4], dtA[2][4];
    for (int c=0;c<2;c++){
      int run = 0;
      for (int r=0;r<4;r++){
        stA[c][r] = (c==0) ? stf[r] : dtf[r];
        dtA[c][r] = (c==0) ? dtf[r] : stf[r];
        koff[c][r] = run;
        run += stA[c][r] ? ni : nd;
      }
    }

    // ---- build 2 merged edge CSRs + function CSR ----
    hipMemsetAsync(OFFS3, 0, (size_t)3*NOR*4, stream);
    HD hd; int hb = 0;
    for (int c2=0; c2<2; c2++)
      for (int r=0; r<4; r++){
        int ent = c2*4 + r;
        hd.blk0[ent] = hb;
        hd.dst[ent] = (c2==0) ? ei[r]+E[r] : ei[r];
        hd.src[ent] = (c2==0) ? ei[r] : ei[r]+E[r];
        hd.E[ent] = E[r];
        hd.cnto[ent] = c2*NOR + (dtA[c2][r] ? nd : 0);
        hd.permo[ent] = c2*(int)EtotM;
        hb += (E[r]+255)/256;
      }
    hd.blk0[8] = hb;
    csr_hist_all_k<<<hb,256,0,stream>>>(hd, OFFS3);
    fhist_k<<<ntb,256,0,stream>>>(fdp, fip, nd, ni, OFFS3 + (size_t)2*NOR);
    ScanDesc sd; sd.n[0] = nrows; sd.n[1] = nrows; sd.n[2] = FFUNC;
    int maxtiles = (nrows + 1023)/1024; if (maxtiles < 1) maxtiles = 1;
    dim3 sgrid(maxtiles, 3);
    scan_p1<<<sgrid,1024,0,stream>>>(sd, OFFS3, PART, NOR, maxtiles);
    scan_p2<<<1,1024,0,stream>>>(PART, maxtiles, 3);
    scan_p3<<<sgrid,1024,0,stream>>>(sd, OFFS3, CURS3, PART, NOR, maxtiles);
    csr_fill_all_k<<<hb,256,0,stream>>>(hd, CURS3, PERM);
    ffill_k<<<ntb,256,0,stream>>>(fdp, fip, nd, ni, CURS3 + (size_t)2*NOR, FPERM);

    for (int l=0; l<2; ++l){
      const void* xd = (l==0) ? (const void*)x0d : (const void*)Xb;
      const void* xi = (l==0) ? (const void*)x0i : (const void*)(Xb + (size_t)nd*128);
      int af32 = (l==0);
      for (int c=0; c<2; ++c){
        int pc = l*2 + c;
        // build output descriptor sets (data / inst)
        KSet kd, ki;
        kd.nout = 1; ki.nout = 1;
        kd.o[0].w = WQP + (size_t)(pc*2+0)*16384;
        kd.o[0].bi = bq + (size_t)(pc*2+0)*128;
        kd.o[0].dst = Qb;
        ki.o[0].w = WQP + (size_t)(pc*2+1)*16384;
        ki.o[0].bi = bq + (size_t)(pc*2+1)*128;
        ki.o[0].dst = Qb + (size_t)nd*128;
        for (int r=0;r<4;r++){
          int cid = (pc*2+c)*4 + r;
          KSet& ks = stA[c][r] ? ki : kd;
          ks.o[ks.nout].w = COMPX + (size_t)cid*16384;
          ks.o[ks.nout].bi = BCX + (size_t)cid*128;
          ks.o[ks.nout].dst = KRK + (size_t)koff[c][r]*128;
          ks.nout++;
          ks.o[ks.nout].w = COMPX + (size_t)(32+cid)*16384;
          ks.o[ks.nout].bi = BCX + (size_t)(32+cid)*128;
          ks.o[ks.nout].dst = KRV + (size_t)koff[c][r]*128;
          ks.nout++;
        }
        gemm_kqvc_k<<<nb,256,0,stream>>>(xd, xi, af32, nd, ni, gbd, kd, ki);
        MD md;
        for (int r=0;r<4;r++) md.koff[r] = koff[c][r];
        int eblk = (nrows*32 + 255)/256;
        e12m_k<<<eblk,256,0,stream>>>(KRK, KRV, Qb,
                                      OFFS3 + (size_t)c*NOR, PERM + (size_t)c*EtotM, nrows,
                                      PRp + (size_t)pc*16, AGGb, DEN, md);
        gemm_epi_k<<<nb,256,0,stream>>>(
            AGGb, DEN, nd, ni, gbd,
            WAP+(size_t)pc*2*16384, ba+(size_t)pc*2*128,
            xd, xi, af32,
            (c==1) ? O1b : (const unsigned short*)nullptr,
            (c==0) ? O1b : Xb,
            SKp + (size_t)pc*2, (c==0) ? 2 : 3);
      }
    }
    // pooling (function-CSR, bf16 X)
    float* fsum = GS[g]+OF_FSUM;  float* fcnt = GS[g]+OF_FCNT;
    float* cf   = GS[g]+OF_CF;    float* attc = GS[g]+OF_ATTC;
    float* pool = GS[g]+OF_POOL;
    hipMemsetAsync(pool, 0, 128*4, stream);
    f1c_k<<<FFUNC,256,0,stream>>>(Xb, OFFS3 + (size_t)2*NOR, FPERM, fsum, fcnt);
    attc2_k<<<1,1024,0,stream>>>(fsum, 1.0f/(float)nrows, WATT, attc);
    gemmb_k<<<(FFUNC+63)/64,256,0,stream>>>(fsum, FFUNC, WATTP, nullptr, cf, 1, fcnt);
    f23c_k<<<FFUNC,256,0,stream>>>(Xb, OFFS3 + (size_t)2*NOR, FPERM, cf, attc, FB[g], pool);
  }
  // similarity histogram + final head
  hist_init_k<<<1,32,0,stream>>>(MM, HIST);
  dim3 gnt((FFUNC+63)/64, (FFUNC+63)/64);
  gemmnt_b<<<gnt,256,0,stream>>>(FB[0], FB[1], SCb, MM);
  hist_k<<<512,256,0,stream>>>(SCb, MM, HIST);
  final_k<<<1,256,0,stream>>>(GS[0]+OF_POOL, GS[1]+OF_POOL, WTN, VTN, BTN, HIST,
                              WFC1, BFC1, WSC, BSC, (float*)d_out);
}